// Round 10
// baseline (2301.972 us; speedup 1.0000x reference)
//
#include <hip/hip_runtime.h>
#include <math.h>

#define N_NODES 30000
#define N_EDGES 480000

typedef __attribute__((ext_vector_type(8))) short s8v;   // 8 x bf16 (as i16 bits)
typedef __attribute__((ext_vector_type(4))) float f4v;

__device__ inline unsigned short f2bf(float f) {  // RNE (weights, staged once)
  union { float f; unsigned u; } v; v.f = f;
  return (unsigned short)((v.u + 0x7fffu + ((v.u >> 16) & 1u)) >> 16);
}
__device__ inline float bfh2f(unsigned short h) {
  union { unsigned u; float f; } v; v.u = (unsigned)h << 16; return v.f;
}
// cheap RTZ hi/lo split: hi+lo captures 16 mantissa bits (err ~2^-16 rel), 4 VALU ops
__device__ inline void split_rtz(float x, unsigned short& hi, unsigned short& lo) {
  unsigned u = __float_as_uint(x);
  hi = (unsigned short)(u >> 16);
  float hf = __uint_as_float(u & 0xffff0000u);
  lo = (unsigned short)(__float_as_uint(x - hf) >> 16);
}
// fast softplus(x) - log2: native exp/log (v_exp_f32/v_log_f32), no branches
__device__ inline float sspf(float x) {
  float t = __expf(-fabsf(x));
  return fmaxf(x, 0.f) + __logf(1.f + t) - 0.69314718055994531f;
}
// LDS XOR swizzle: stride 64 shorts/row, spread rows across bank windows.
// 8-aligned k-blocks stay contiguous (XOR value is a multiple of 8).
__device__ inline int swz(int row, int k) { return k ^ ((row & 7) << 3); }

// ---------------- CSR build (once per launch; edge_dst identical across layers) ----------------
__global__ __launch_bounds__(256) void k_hist(const int* __restrict__ edst, int* __restrict__ counts) {
  int e = blockIdx.x * 256 + threadIdx.x;
  if (e < N_EDGES) atomicAdd(&counts[edst[e]], 1);
}

#define SCAN_T 1024
#define NPER 30
__global__ __launch_bounds__(1024) void k_scan(const int* __restrict__ counts,
                                               int* __restrict__ row_start, int* __restrict__ cursor) {
  __shared__ int part[SCAN_T];
  int t = threadIdx.x;
  int base = t * NPER;
  int local[NPER];
  int s = 0;
#pragma unroll
  for (int j = 0; j < NPER; ++j) {
    int idx = base + j;
    int c = (idx < N_NODES) ? counts[idx] : 0;
    local[j] = s;
    s += c;
  }
  part[t] = s;
  __syncthreads();
  for (int off = 1; off < SCAN_T; off <<= 1) {
    int v = (t >= off) ? part[t - off] : 0;
    __syncthreads();
    part[t] += v;
    __syncthreads();
  }
  int pre = (t == 0) ? 0 : part[t - 1];
#pragma unroll
  for (int j = 0; j < NPER; ++j) {
    int idx = base + j;
    if (idx < N_NODES) {
      int v = pre + local[j];
      row_start[idx] = v;
      cursor[idx] = v;
    }
  }
  if (t == SCAN_T - 1) row_start[N_NODES] = pre + s;
}

__global__ __launch_bounds__(256) void k_scatter(const int* __restrict__ edst,
                                                 int* __restrict__ cursor, int* __restrict__ eidx) {
  int e = blockIdx.x * 256 + threadIdx.x;
  if (e < N_EDGES) {
    int pos = atomicAdd(&cursor[edst[e]], 1);
    eidx[pos] = e;
  }
}

// fallback (no-MAT): sort each segment for determinism
__global__ __launch_bounds__(256) void k_sortseg(const int* __restrict__ row_start, int* __restrict__ eidx) {
  int wid = (blockIdx.x * 256 + threadIdx.x) >> 6;
  int lane = threadIdx.x & 63;
  if (wid >= N_NODES) return;
  int jb = row_start[wid], je = row_start[wid + 1];
  int deg = je - jb;
  if (deg <= 1) return;
  if (deg <= 64) {
    int key = (lane < deg) ? eidx[jb + lane] : 0x7fffffff;
#pragma unroll
    for (int k = 2; k <= 64; k <<= 1)
      for (int j = k >> 1; j > 0; j >>= 1) {
        int other = __shfl_xor(key, j, 64);
        bool asc = ((lane & k) == 0);
        bool upper = ((lane & j) != 0);
        key = (upper == asc) ? max(key, other) : min(key, other);
      }
    if (lane < deg) eidx[jb + lane] = key;
  } else if (lane == 0) {
    for (int i = jb + 1; i < je; ++i) {
      int v = eidx[i];
      int j = i - 1;
      while (j >= jb && eidx[j] > v) { eidx[j + 1] = eidx[j]; --j; }
      eidx[j + 1] = v;
    }
  }
}

// ---------------- fused sort + materialize (1 wave = 1 dst node, once per launch) ------------
__global__ __launch_bounds__(256) void k_sortmat(const int* __restrict__ row_start, int* __restrict__ eidx,
    const int* __restrict__ esrc, const float* __restrict__ esc, const float* __restrict__ eattr,
    unsigned short* __restrict__ esc_hl, float4* __restrict__ y_s, int* __restrict__ src_s) {
  int wid = (blockIdx.x * 256 + threadIdx.x) >> 6;
  int lane = threadIdx.x & 63;
  if (wid >= N_NODES) return;
  int jb = row_start[wid], je = row_start[wid + 1];
  int deg = je - jb;
  if (deg <= 0) return;
  if (deg <= 64) {
    int key = (lane < deg) ? eidx[jb + lane] : 0x7fffffff;
#pragma unroll
    for (int k = 2; k <= 64; k <<= 1)
      for (int j = k >> 1; j > 0; j >>= 1) {
        int other = __shfl_xor(key, j, 64);
        bool asc = ((lane & k) == 0);
        bool upper = ((lane & j) != 0);
        key = (upper == asc) ? max(key, other) : min(key, other);
      }
    if (lane < deg) {
      int p = jb + lane, e = key;
      src_s[p] = esrc[e];
      y_s[p] = *(const float4*)(eattr + (size_t)e * 4);
      const float4* q = (const float4*)(esc + (size_t)e * 8);
      float4 a = q[0], b = q[1];
      float e8[8] = {a.x, a.y, a.z, a.w, b.x, b.y, b.z, b.w};
      s8v hi, lo;
#pragma unroll
      for (int j = 0; j < 8; ++j) {
        unsigned short h, l;
        split_rtz(e8[j], h, l);
        hi[j] = (short)h; lo[j] = (short)l;
      }
      *(s8v*)(esc_hl + (size_t)p * 16) = hi;
      *(s8v*)(esc_hl + (size_t)p * 16 + 8) = lo;
    }
  } else {
    if (lane == 0) {  // rare fallback
      for (int i = jb + 1; i < je; ++i) {
        int v = eidx[i];
        int j = i - 1;
        while (j >= jb && eidx[j] > v) { eidx[j + 1] = eidx[j]; --j; }
        eidx[j + 1] = v;
      }
    }
    for (int p = jb + lane; p < je; p += 64) {
      int e = eidx[p];
      src_s[p] = esrc[e];
      y_s[p] = *(const float4*)(eattr + (size_t)e * 4);
      const float4* q = (const float4*)(esc + (size_t)e * 8);
      float4 a = q[0], b = q[1];
      float e8[8] = {a.x, a.y, a.z, a.w, b.x, b.y, b.z, b.w};
      s8v hi, lo;
#pragma unroll
      for (int j = 0; j < 8; ++j) {
        unsigned short h, l;
        split_rtz(e8[j], h, l);
        hi[j] = (short)h; lo[j] = (short)l;
      }
      *(s8v*)(esc_hl + (size_t)p * 16) = hi;
      *(s8v*)(esc_hl + (size_t)p * 16 + 8) = lo;
    }
  }
}

// ---------------- node_pre: low-divergence compute, permuted store into interleaved layout -------
__global__ __launch_bounds__(256) void k_node_pre(const float* __restrict__ x,
    const float* __restrict__ l1s, const float* __restrict__ l1v,
    float* __restrict__ s1v1)
{
  int t = blockIdx.x * 256 + threadIdx.x;
  int node = t >> 7, j = t & 127;
  const float* xr = x + (size_t)node * 128;
  float acc = 0.f;
  int addr;
  if (j < 32) {
    int m = j;
#pragma unroll
    for (int u = 0; u < 32; ++u) acc += xr[u] * l1s[u * 32 + m];
    addr = (m & 15) * 8 + (m >> 4);
  } else {
    int jj = j - 32, m = jj / 3, c = jj - 3 * m;
#pragma unroll
    for (int u = 0; u < 32; ++u) acc += xr[32 + u * 3 + c] * l1v[u * 32 + m];
    addr = (m & 15) * 8 + 2 + (m >> 4) * 3 + c;
  }
  s1v1[(size_t)node * 128 + addr] = acc * 0.17677669529663689f;
}

// ---------------- fused edge MLP + per-node aggregation (1 wave = 1 dst node, no atomics) --------
// R10: B-frags back to per-tile LDS reads (R8 codegen, low VGPR); pad-row skip kept; LDS stride
// 72->64 shorts with XOR swizzle (same bank spread, bitwise-identical values) -> 40960 B = 4 blk/CU.
template<int MAT>
__global__ __launch_bounds__(256, 4) void k_edge_agg(
    const float* __restrict__ esc, const int* __restrict__ esrc, const float* __restrict__ eattr,
    const unsigned short* __restrict__ esc_hl, const int* __restrict__ src_s, const float4* __restrict__ y_s,
    const float* __restrict__ s1v1, const int* __restrict__ row_start, const int* __restrict__ eidx,
    const float* __restrict__ w1g, const float* __restrict__ w2g, const float* __restrict__ w3g,
    float* __restrict__ agg)
{
  __shared__ __attribute__((aligned(16))) unsigned short W2T[64 * 64];
  __shared__ __attribute__((aligned(16))) unsigned short W3T[128 * 64];
  __shared__ __attribute__((aligned(16))) unsigned short Hb[4][2][16 * 64];

  const int tid = threadIdx.x, lane = tid & 63, wv = tid >> 6;
  const int c0 = lane & 15, g = lane >> 4;

  for (int idx = tid; idx < 64 * 64; idx += 256) {
    int k = idx >> 6, n2 = idx & 63;
    W2T[n2 * 64 + swz(n2, k)] = f2bf(w2g[idx] * 0.125f);      // exact pow2 fold
  }
  for (int idx = tid; idx < 64 * 128; idx += 256) {
    int k = idx >> 7, n2 = idx & 127;
    W3T[n2 * 64 + swz(n2, k)] = f2bf(w3g[idx] * 0.125f);      // exact pow2 fold
  }
  // B1 carries 1/sqrt(8): hi/lo split of the scaled weight
  s8v B1[4];
#pragma unroll
  for (int nt = 0; nt < 4; ++nt)
#pragma unroll
    for (int i = 0; i < 8; ++i) {
      float w = w1g[i * 64 + nt * 16 + c0] * 0.35355339059327373f;
      unsigned short hi = f2bf(w);
      B1[nt][i] = (g < 2) ? (short)hi : (short)f2bf(w - bfh2f(hi));
    }
  __syncthreads();   // only block-wide barrier (weight staging)

  unsigned short* hhi = &Hb[wv][0][0];
  unsigned short* hlo = &Hb[wv][1][0];
  const f4v z = {0.f, 0.f, 0.f, 0.f};

  const int node = blockIdx.x * 4 + wv;
  const int jb = row_start[node], je = row_start[node + 1];

  float nacc[16];
#pragma unroll
  for (int k = 0; k < 16; ++k) nacc[k] = 0.f;

  for (int base = jb; base < je; base += 16) {
    const int nvalid = je - base;
    // ---- prefetch per-edge data
    s8v A1 = {0, 0, 0, 0, 0, 0, 0, 0};
    int srcv[4];
    float4 yv[4];
    bool val[4];
    if constexpr (MAT) {
      if (c0 < nvalid)
        A1 = *(const s8v*)(esc_hl + (size_t)(base + c0) * 16 + (size_t)(g & 1) * 8);
#pragma unroll
      for (int i = 0; i < 4; ++i) {
        int s = g * 4 + i;
        val[i] = (s < nvalid);
        srcv[i] = 0; yv[i] = make_float4(0.f, 0.f, 0.f, 0.f);
        if (val[i]) { srcv[i] = src_s[base + s]; yv[i] = y_s[base + s]; }
      }
    } else {
      if (c0 < nvalid) {
        int eid = eidx[base + c0];
        const float4* p = (const float4*)(esc + (size_t)eid * 8);
        float4 a = p[0], b = p[1];
        float e8[8] = {a.x, a.y, a.z, a.w, b.x, b.y, b.z, b.w};
#pragma unroll
        for (int j = 0; j < 8; ++j) {
          unsigned short h, l;
          split_rtz(e8[j], h, l);
          A1[j] = (g & 1) ? (short)l : (short)h;
        }
      }
#pragma unroll
      for (int i = 0; i < 4; ++i) {
        int s = g * 4 + i;
        val[i] = (s < nvalid);
        srcv[i] = 0; yv[i] = make_float4(0.f, 0.f, 0.f, 0.f);
        if (val[i]) {
          int eid = eidx[base + s];
          srcv[i] = esrc[eid];
          yv[i] = *(const float4*)(eattr + (size_t)eid * 4);
        }
      }
    }
    // ---- stage 1: h1 = ssp(es @ W1s); pad rows skipped (stale values never consumed)
#pragma unroll
    for (int nt = 0; nt < 4; ++nt) {
      f4v acc = __builtin_amdgcn_mfma_f32_16x16x32_bf16(A1, B1[nt], z, 0, 0, 0);
#pragma unroll
      for (int i = 0; i < 4; ++i) {
        int r = g * 4 + i;
        if (r < nvalid) {
          float hv = sspf(acc[i]);
          unsigned short h, l;
          split_rtz(hv, h, l);
          hhi[r * 64 + swz(r, nt * 16 + c0)] = h;
          hlo[r * 64 + swz(r, nt * 16 + c0)] = l;
        }
      }
    }
    // ---- stage 2: h2 = ssp(h1 @ W2s) (per-wave in-order DS; frags loaded before overwrite)
    s8v A2ah = *(const s8v*)&hhi[c0 * 64 + swz(c0, 8 * g)];
    s8v A2bh = *(const s8v*)&hhi[c0 * 64 + swz(c0, 32 + 8 * g)];
    s8v A2al = *(const s8v*)&hlo[c0 * 64 + swz(c0, 8 * g)];
    s8v A2bl = *(const s8v*)&hlo[c0 * 64 + swz(c0, 32 + 8 * g)];
#pragma unroll
    for (int nt = 0; nt < 4; ++nt) {
      s8v Ba = *(const s8v*)&W2T[(nt * 16 + c0) * 64 + swz(c0, 8 * g)];
      s8v Bb = *(const s8v*)&W2T[(nt * 16 + c0) * 64 + swz(c0, 32 + 8 * g)];
      f4v acc = __builtin_amdgcn_mfma_f32_16x16x32_bf16(A2ah, Ba, z, 0, 0, 0);
      acc = __builtin_amdgcn_mfma_f32_16x16x32_bf16(A2bh, Bb, acc, 0, 0, 0);
      acc = __builtin_amdgcn_mfma_f32_16x16x32_bf16(A2al, Ba, acc, 0, 0, 0);
      acc = __builtin_amdgcn_mfma_f32_16x16x32_bf16(A2bl, Bb, acc, 0, 0, 0);
#pragma unroll
      for (int i = 0; i < 4; ++i) {
        int r = g * 4 + i;
        if (r < nvalid) {
          float hv = sspf(acc[i]);
          unsigned short h, l;
          split_rtz(hv, h, l);
          hhi[r * 64 + swz(r, nt * 16 + c0)] = h;
          hlo[r * 64 + swz(r, nt * 16 + c0)] = l;
        }
      }
    }
    // ---- s1v1 row loads before stage 3 (latency hides under MFMAs)
    float4 pr0[4], pr1[4];
#pragma unroll
    for (int i = 0; i < 4; ++i) {
      if (val[i]) {
        const float* svp = s1v1 + (size_t)srcv[i] * 128 + c0 * 8;
        pr0[i] = *(const float4*)svp;
        pr1[i] = *(const float4*)(svp + 4);
      } else {
        pr0[i] = make_float4(0.f, 0.f, 0.f, 0.f);
        pr1[i] = make_float4(0.f, 0.f, 0.f, 0.f);
      }
    }
    // ---- stage 3: w = h2 @ W3s
    s8v A3ah = *(const s8v*)&hhi[c0 * 64 + swz(c0, 8 * g)];
    s8v A3bh = *(const s8v*)&hhi[c0 * 64 + swz(c0, 32 + 8 * g)];
    s8v A3al = *(const s8v*)&hlo[c0 * 64 + swz(c0, 8 * g)];
    s8v A3bl = *(const s8v*)&hlo[c0 * 64 + swz(c0, 32 + 8 * g)];
    f4v acc3[8];
#pragma unroll
    for (int nt = 0; nt < 8; ++nt) {
      s8v Ba = *(const s8v*)&W3T[(nt * 16 + c0) * 64 + swz(c0, 8 * g)];
      s8v Bb = *(const s8v*)&W3T[(nt * 16 + c0) * 64 + swz(c0, 32 + 8 * g)];
      acc3[nt] = __builtin_amdgcn_mfma_f32_16x16x32_bf16(A3ah, Ba, z, 0, 0, 0);
      acc3[nt] = __builtin_amdgcn_mfma_f32_16x16x32_bf16(A3bh, Bb, acc3[nt], 0, 0, 0);
      acc3[nt] = __builtin_amdgcn_mfma_f32_16x16x32_bf16(A3al, Ba, acc3[nt], 0, 0, 0);
      acc3[nt] = __builtin_amdgcn_mfma_f32_16x16x32_bf16(A3bl, Bb, acc3[nt], 0, 0, 0);
    }
    // ---- epilogue: accumulate per-lane partials (reduce deferred to end of node)
#pragma unroll
    for (int i = 0; i < 4; ++i) {
      if (val[i]) {
        float w0 = acc3[0][i], w1_ = acc3[1][i], w2_ = acc3[2][i], w3_ = acc3[3][i];
        float w4_ = acc3[4][i], w5_ = acc3[5][i], w6_ = acc3[6][i], w7_ = acc3[7][i];
        float4 y = yv[i];
        float sA = pr0[i].x, sB = pr0[i].y;
        float vA0 = pr0[i].z, vA1 = pr0[i].w, vA2 = pr1[i].x;
        float vB0 = pr1[i].y, vB1 = pr1[i].z, vB2 = pr1[i].w;
        nacc[0] += w0 * sA * y.x;
        nacc[1] += w1_ * sB * y.x;
        nacc[2] += w6_ * (vA0 * y.y + vA1 * y.z + vA2 * y.w);
        nacc[3] += w7_ * (vB0 * y.y + vB1 * y.z + vB2 * y.w);
        nacc[4] += w2_ * sA * y.y;  nacc[5] += w2_ * sA * y.z;  nacc[6] += w2_ * sA * y.w;
        nacc[7] += w3_ * sB * y.y;  nacc[8] += w3_ * sB * y.z;  nacc[9] += w3_ * sB * y.w;
        nacc[10] += w4_ * vA0 * y.x; nacc[11] += w4_ * vA1 * y.x; nacc[12] += w4_ * vA2 * y.x;
        nacc[13] += w5_ * vB0 * y.x; nacc[14] += w5_ * vB1 * y.x; nacc[15] += w5_ * vB2 * y.x;
      }
    }
  }
  // ---- one cross-lane reduce per node
#pragma unroll
  for (int k = 0; k < 16; ++k) {
    float v = nacc[k];
    v += __shfl_xor(v, 16, 64);
    v += __shfl_xor(v, 32, 64);
    nacc[k] = v;
  }
  if (g == 0) {
    float* ad = agg + (size_t)node * 256;
    ad[c0] = nacc[0];
    ad[16 + c0] = nacc[1];
    ad[32 + c0] = nacc[2];
    ad[48 + c0] = nacc[3];
#pragma unroll
    for (int c = 0; c < 3; ++c) {
      ad[64 + 3 * c0 + c]  = nacc[4 + c];
      ad[112 + 3 * c0 + c] = nacc[7 + c];
      ad[160 + 3 * c0 + c] = nacc[10 + c];
      ad[208 + 3 * c0 + c] = nacc[13 + c];
    }
  }
}

// ---------------- node_post: lin2 + self-connection + gate + residual ----------------
__global__ __launch_bounds__(256) void k_node_post(
    const float* __restrict__ x, const float* __restrict__ attr, const float* __restrict__ agg,
    const float* __restrict__ l2s, const float* __restrict__ l2v,
    const float* __restrict__ scs, const float* __restrict__ scv,
    float* __restrict__ out)
{
  __shared__ float xa[4][4][136];
  __shared__ float ag[4][4][256];
  const int l = threadIdx.x & 63, wv = threadIdx.x >> 6;
  const int n0 = blockIdx.x * 16 + wv * 4;
#pragma unroll
  for (int b = 0; b < 4; ++b) {
    int nd = n0 + b;
    xa[wv][b][l] = x[(size_t)nd * 128 + l];
    xa[wv][b][64 + l] = x[(size_t)nd * 128 + 64 + l];
    if (l < 8) xa[wv][b][128 + l] = attr[nd * 8 + l];
#pragma unroll
    for (int q = 0; q < 4; ++q) ag[wv][b][q * 64 + l] = agg[(size_t)nd * 256 + q * 64 + l];
  }
  float attr_r[4][8];
#pragma unroll
  for (int b = 0; b < 4; ++b)
#pragma unroll
    for (int a = 0; a < 8; ++a) attr_r[b][a] = xa[wv][b][128 + a];

  const int w1 = l / 3, c1 = l - 3 * w1;
  const int f2 = 64 + l;
  const int w2r = f2 / 3, c2r = f2 - 3 * w2r;
  const int w2 = (l < 32) ? w2r : 0, c2 = (l < 32) ? c2r : 0;

  float acc[4] = {0.f, 0.f, 0.f, 0.f}, sa[4] = {0.f, 0.f, 0.f, 0.f};
  float av1[4] = {0.f, 0.f, 0.f, 0.f}, sv1[4] = {0.f, 0.f, 0.f, 0.f};
  float av2[4] = {0.f, 0.f, 0.f, 0.f}, sv2[4] = {0.f, 0.f, 0.f, 0.f};

#pragma unroll 8
  for (int u = 0; u < 64; ++u) {
    float wl = l2s[u * 64 + l];
#pragma unroll
    for (int b = 0; b < 4; ++b) acc[b] += ag[wv][b][u] * wl;
  }
#pragma unroll 4
  for (int u = 0; u < 64; ++u) {
    float wla = l2v[u * 32 + w1];
    float wlb = l2v[u * 32 + w2];
#pragma unroll
    for (int b = 0; b < 4; ++b) {
      av1[b] += ag[wv][b][64 + 3 * u + c1] * wla;
      av2[b] += ag[wv][b][64 + 3 * u + c2] * wlb;
    }
  }
  for (int u = 0; u < 32; ++u) {
    float sb[4];
#pragma unroll
    for (int b = 0; b < 4; ++b) sb[b] = xa[wv][b][u];
#pragma unroll
    for (int a = 0; a < 8; ++a) {
      float wl = scs[(u * 8 + a) * 64 + l];
#pragma unroll
      for (int b = 0; b < 4; ++b) sa[b] += sb[b] * attr_r[b][a] * wl;
    }
  }
  for (int u = 0; u < 32; ++u) {
    float vb1[4], vb2[4];
#pragma unroll
    for (int b = 0; b < 4; ++b) {
      vb1[b] = xa[wv][b][32 + 3 * u + c1];
      vb2[b] = xa[wv][b][32 + 3 * u + c2];
    }
#pragma unroll
    for (int a = 0; a < 8; ++a) {
      float wla = scv[(u * 8 + a) * 32 + w1];
      float wlb = scv[(u * 8 + a) * 32 + w2];
#pragma unroll
      for (int b = 0; b < 4; ++b) {
        sv1[b] += vb1[b] * attr_r[b][a] * wla;
        sv2[b] += vb2[b] * attr_r[b][a] * wlb;
      }
    }
  }

#pragma unroll
  for (int b = 0; b < 4; ++b) {
    float outs = acc[b] * 0.03125f + sa[b] * 0.0625f;
    float gss = sspf(outs);
    float ov1 = av1[b] * 0.03125f + sv1[b] * 0.0625f;
    float ov2 = av2[b] * 0.03125f + sv2[b] * 0.0625f;
    float gate1 = __shfl(gss, 32 + w1, 64);
    float gate2 = __shfl(gss, 32 + w2, 64);
    float* o = out + (size_t)(n0 + b) * 128;
    if (l < 32) o[l] = xa[wv][b][l] + gss;
    o[32 + l] = xa[wv][b][32 + l] + ov1 * gate1;
    if (l < 32) o[96 + l] = xa[wv][b][96 + l] + ov2 * gate2;
  }
}

extern "C" void kernel_launch(void* const* d_in, const int* in_sizes, int n_in,
                              void* d_out, int out_size, void* d_ws, size_t ws_size,
                              hipStream_t stream) {
  const float* node_input = (const float*)d_in[0];
  const float* node_attr  = (const float*)d_in[1];
  const int*   esrc  = (const int*)d_in[2];
  const int*   edst  = (const int*)d_in[3];
  const float* eattr = (const float*)d_in[4];
  const float* escal = (const float*)d_in[5];
  const float* l1s = (const float*)d_in[6];
  const float* l1v = (const float*)d_in[7];
  const float* w1  = (const float*)d_in[8];
  const float* w2  = (const float*)d_in[9];
  const float* w3  = (const float*)d_in[10];
  const float* l2s = (const float*)d_in[11];
  const float* l2v = (const float*)d_in[12];
  const float* scs = (const float*)d_in[13];
  const float* scv = (const float*)d_in[14];
  float* out  = (float*)d_out;

  char* p = (char*)d_ws;
  float* s1v1 = (float*)p;                 p += (size_t)N_NODES * 128 * 4;
  float* agg  = (float*)p;                 p += (size_t)N_NODES * 256 * 4;
  int* eidx   = (int*)p;                   p += (size_t)N_EDGES * 4;
  unsigned short* esc_hl = (unsigned short*)p;  p += (size_t)N_EDGES * 16 * 2;
  float4* y_s = (float4*)p;                p += (size_t)N_EDGES * 16;
  int* src_s  = (int*)p;                   p += (size_t)N_EDGES * 4;
  size_t need_mat = (size_t)(p - (char*)d_ws) + (size_t)(N_NODES * 2 + 1) * 4;
  char* tail = ((size_t)ws_size >= need_mat) ? p : (char*)(eidx + N_EDGES);
  int* counts    = (int*)tail;
  int* row_start = counts + N_NODES;
  int* cursor    = row_start + N_NODES + 1;
  const bool use_mat = ((size_t)ws_size >= need_mat);

  (void)hipMemsetAsync(counts, 0, (size_t)N_NODES * sizeof(int), stream);
  k_hist<<<(N_EDGES + 255) / 256, 256, 0, stream>>>(edst, counts);
  k_scan<<<1, SCAN_T, 0, stream>>>(counts, row_start, cursor);
  k_scatter<<<(N_EDGES + 255) / 256, 256, 0, stream>>>(edst, cursor, eidx);
  if (use_mat)
    k_sortmat<<<(N_NODES * 64 + 255) / 256, 256, 0, stream>>>(row_start, eidx,
        esrc, escal, eattr, esc_hl, y_s, src_s);
  else
    k_sortseg<<<(N_NODES * 64 + 255) / 256, 256, 0, stream>>>(row_start, eidx);

  for (int layer = 0; layer < 3; ++layer) {
    const float* xin = (layer == 0) ? node_input : (const float*)out;
    k_node_pre<<<N_NODES * 128 / 256, 256, 0, stream>>>(
        xin, l1s + layer * 1024, l1v + layer * 1024, s1v1);
    if (use_mat)
      k_edge_agg<1><<<N_NODES / 4, 256, 0, stream>>>(escal, esrc, eattr, esc_hl, src_s, y_s,
          s1v1, row_start, eidx, w1 + layer * 512, w2 + layer * 4096, w3 + layer * 8192, agg);
    else
      k_edge_agg<0><<<N_NODES / 4, 256, 0, stream>>>(escal, esrc, eattr, esc_hl, src_s, y_s,
          s1v1, row_start, eidx, w1 + layer * 512, w2 + layer * 4096, w3 + layer * 8192, agg);
    k_node_post<<<N_NODES / 16, 256, 0, stream>>>(xin, node_attr, agg,
        l2s + layer * 4096, l2v + layer * 2048, scs + layer * 16384, scv + layer * 8192, out);
  }
}

// Round 11
// 2198.260 us; speedup vs baseline: 1.0472x; 1.0472x over previous
//
#include <hip/hip_runtime.h>
#include <math.h>

#define N_NODES 30000
#define N_EDGES 480000

typedef __attribute__((ext_vector_type(8))) short s8v;   // 8 x bf16 (as i16 bits)
typedef __attribute__((ext_vector_type(4))) float f4v;

__device__ inline unsigned short f2bf(float f) {  // RNE (weights, staged once)
  union { float f; unsigned u; } v; v.f = f;
  return (unsigned short)((v.u + 0x7fffu + ((v.u >> 16) & 1u)) >> 16);
}
__device__ inline float bfh2f(unsigned short h) {
  union { unsigned u; float f; } v; v.u = (unsigned)h << 16; return v.f;
}
// cheap RTZ hi/lo split: hi+lo captures 16 mantissa bits (err ~2^-16 rel), 4 VALU ops
__device__ inline void split_rtz(float x, unsigned short& hi, unsigned short& lo) {
  unsigned u = __float_as_uint(x);
  hi = (unsigned short)(u >> 16);
  float hf = __uint_as_float(u & 0xffff0000u);
  lo = (unsigned short)(__float_as_uint(x - hf) >> 16);
}
// fast softplus(x) - log2: native exp/log (v_exp_f32/v_log_f32), no branches
__device__ inline float sspf(float x) {
  float t = __expf(-fabsf(x));
  return fmaxf(x, 0.f) + __logf(1.f + t) - 0.69314718055994531f;
}
// LDS XOR swizzle: stride 64 shorts/row; 8-aligned k-blocks stay contiguous.
__device__ inline int swz(int row, int k) { return k ^ ((row & 7) << 3); }

// ---------------- CSR build (once per launch; edge_dst identical across layers) ----------------
__global__ __launch_bounds__(256) void k_hist(const int* __restrict__ edst, int* __restrict__ counts) {
  int e = blockIdx.x * 256 + threadIdx.x;
  if (e < N_EDGES) atomicAdd(&counts[edst[e]], 1);
}

#define SCAN_T 1024
#define NPER 30
__global__ __launch_bounds__(1024) void k_scan(const int* __restrict__ counts,
                                               int* __restrict__ row_start, int* __restrict__ cursor) {
  __shared__ int part[SCAN_T];
  int t = threadIdx.x;
  int base = t * NPER;
  int local[NPER];
  int s = 0;
#pragma unroll
  for (int j = 0; j < NPER; ++j) {
    int idx = base + j;
    int c = (idx < N_NODES) ? counts[idx] : 0;
    local[j] = s;
    s += c;
  }
  part[t] = s;
  __syncthreads();
  for (int off = 1; off < SCAN_T; off <<= 1) {
    int v = (t >= off) ? part[t - off] : 0;
    __syncthreads();
    part[t] += v;
    __syncthreads();
  }
  int pre = (t == 0) ? 0 : part[t - 1];
#pragma unroll
  for (int j = 0; j < NPER; ++j) {
    int idx = base + j;
    if (idx < N_NODES) {
      int v = pre + local[j];
      row_start[idx] = v;
      cursor[idx] = v;
    }
  }
  if (t == SCAN_T - 1) row_start[N_NODES] = pre + s;
}

__global__ __launch_bounds__(256) void k_scatter(const int* __restrict__ edst,
                                                 int* __restrict__ cursor, int* __restrict__ eidx) {
  int e = blockIdx.x * 256 + threadIdx.x;
  if (e < N_EDGES) {
    int pos = atomicAdd(&cursor[edst[e]], 1);
    eidx[pos] = e;
  }
}

// fallback (no-MAT): sort each segment for determinism
__global__ __launch_bounds__(256) void k_sortseg(const int* __restrict__ row_start, int* __restrict__ eidx) {
  int wid = (blockIdx.x * 256 + threadIdx.x) >> 6;
  int lane = threadIdx.x & 63;
  if (wid >= N_NODES) return;
  int jb = row_start[wid], je = row_start[wid + 1];
  int deg = je - jb;
  if (deg <= 1) return;
  if (deg <= 64) {
    int key = (lane < deg) ? eidx[jb + lane] : 0x7fffffff;
#pragma unroll
    for (int k = 2; k <= 64; k <<= 1)
      for (int j = k >> 1; j > 0; j >>= 1) {
        int other = __shfl_xor(key, j, 64);
        bool asc = ((lane & k) == 0);
        bool upper = ((lane & j) != 0);
        key = (upper == asc) ? max(key, other) : min(key, other);
      }
    if (lane < deg) eidx[jb + lane] = key;
  } else if (lane == 0) {
    for (int i = jb + 1; i < je; ++i) {
      int v = eidx[i];
      int j = i - 1;
      while (j >= jb && eidx[j] > v) { eidx[j + 1] = eidx[j]; --j; }
      eidx[j + 1] = v;
    }
  }
}

// ---------------- fused sort + materialize (1 wave = 1 dst node, once per launch) ------------
__global__ __launch_bounds__(256) void k_sortmat(const int* __restrict__ row_start, int* __restrict__ eidx,
    const int* __restrict__ esrc, const float* __restrict__ esc, const float* __restrict__ eattr,
    unsigned short* __restrict__ esc_hl, float4* __restrict__ y_s, int* __restrict__ src_s) {
  int wid = (blockIdx.x * 256 + threadIdx.x) >> 6;
  int lane = threadIdx.x & 63;
  if (wid >= N_NODES) return;
  int jb = row_start[wid], je = row_start[wid + 1];
  int deg = je - jb;
  if (deg <= 0) return;
  if (deg <= 64) {
    int key = (lane < deg) ? eidx[jb + lane] : 0x7fffffff;
#pragma unroll
    for (int k = 2; k <= 64; k <<= 1)
      for (int j = k >> 1; j > 0; j >>= 1) {
        int other = __shfl_xor(key, j, 64);
        bool asc = ((lane & k) == 0);
        bool upper = ((lane & j) != 0);
        key = (upper == asc) ? max(key, other) : min(key, other);
      }
    if (lane < deg) {
      int p = jb + lane, e = key;
      src_s[p] = esrc[e];
      y_s[p] = *(const float4*)(eattr + (size_t)e * 4);
      const float4* q = (const float4*)(esc + (size_t)e * 8);
      float4 a = q[0], b = q[1];
      float e8[8] = {a.x, a.y, a.z, a.w, b.x, b.y, b.z, b.w};
      s8v hi, lo;
#pragma unroll
      for (int j = 0; j < 8; ++j) {
        unsigned short h, l;
        split_rtz(e8[j], h, l);
        hi[j] = (short)h; lo[j] = (short)l;
      }
      *(s8v*)(esc_hl + (size_t)p * 16) = hi;
      *(s8v*)(esc_hl + (size_t)p * 16 + 8) = lo;
    }
  } else {
    if (lane == 0) {  // rare fallback
      for (int i = jb + 1; i < je; ++i) {
        int v = eidx[i];
        int j = i - 1;
        while (j >= jb && eidx[j] > v) { eidx[j + 1] = eidx[j]; --j; }
        eidx[j + 1] = v;
      }
    }
    for (int p = jb + lane; p < je; p += 64) {
      int e = eidx[p];
      src_s[p] = esrc[e];
      y_s[p] = *(const float4*)(eattr + (size_t)e * 4);
      const float4* q = (const float4*)(esc + (size_t)e * 8);
      float4 a = q[0], b = q[1];
      float e8[8] = {a.x, a.y, a.z, a.w, b.x, b.y, b.z, b.w};
      s8v hi, lo;
#pragma unroll
      for (int j = 0; j < 8; ++j) {
        unsigned short h, l;
        split_rtz(e8[j], h, l);
        hi[j] = (short)h; lo[j] = (short)l;
      }
      *(s8v*)(esc_hl + (size_t)p * 16) = hi;
      *(s8v*)(esc_hl + (size_t)p * 16 + 8) = lo;
    }
  }
}

// ---------------- node_pre: low-divergence compute, permuted store into interleaved layout -------
__global__ __launch_bounds__(256) void k_node_pre(const float* __restrict__ x,
    const float* __restrict__ l1s, const float* __restrict__ l1v,
    float* __restrict__ s1v1)
{
  int t = blockIdx.x * 256 + threadIdx.x;
  int node = t >> 7, j = t & 127;
  const float* xr = x + (size_t)node * 128;
  float acc = 0.f;
  int addr;
  if (j < 32) {
    int m = j;
#pragma unroll
    for (int u = 0; u < 32; ++u) acc += xr[u] * l1s[u * 32 + m];
    addr = (m & 15) * 8 + (m >> 4);
  } else {
    int jj = j - 32, m = jj / 3, c = jj - 3 * m;
#pragma unroll
    for (int u = 0; u < 32; ++u) acc += xr[32 + u * 3 + c] * l1v[u * 32 + m];
    addr = (m & 15) * 8 + 2 + (m >> 4) * 3 + c;
  }
  s1v1[(size_t)node * 128 + addr] = acc * 0.17677669529663689f;
}

// ---------------- fused edge MLP + per-node aggregation (1 wave = 1 dst node, no atomics) --------
// R11: R10 body, but __launch_bounds__(256,3) — (256,4) capped VGPR at 64 and spilled ~2GB/dispatch
// to scratch (R10 counters: FETCH 898MB, WRITE 1073MB). 3 waves/SIMD -> natural ~84 VGPR, no spill.
template<int MAT>
__global__ __launch_bounds__(256, 3) void k_edge_agg(
    const float* __restrict__ esc, const int* __restrict__ esrc, const float* __restrict__ eattr,
    const unsigned short* __restrict__ esc_hl, const int* __restrict__ src_s, const float4* __restrict__ y_s,
    const float* __restrict__ s1v1, const int* __restrict__ row_start, const int* __restrict__ eidx,
    const float* __restrict__ w1g, const float* __restrict__ w2g, const float* __restrict__ w3g,
    float* __restrict__ agg)
{
  __shared__ __attribute__((aligned(16))) unsigned short W2T[64 * 64];
  __shared__ __attribute__((aligned(16))) unsigned short W3T[128 * 64];
  __shared__ __attribute__((aligned(16))) unsigned short Hb[4][2][16 * 64];

  const int tid = threadIdx.x, lane = tid & 63, wv = tid >> 6;
  const int c0 = lane & 15, g = lane >> 4;

  for (int idx = tid; idx < 64 * 64; idx += 256) {
    int k = idx >> 6, n2 = idx & 63;
    W2T[n2 * 64 + swz(n2, k)] = f2bf(w2g[idx] * 0.125f);      // exact pow2 fold
  }
  for (int idx = tid; idx < 64 * 128; idx += 256) {
    int k = idx >> 7, n2 = idx & 127;
    W3T[n2 * 64 + swz(n2, k)] = f2bf(w3g[idx] * 0.125f);      // exact pow2 fold
  }
  // B1 carries 1/sqrt(8): hi/lo split of the scaled weight
  s8v B1[4];
#pragma unroll
  for (int nt = 0; nt < 4; ++nt)
#pragma unroll
    for (int i = 0; i < 8; ++i) {
      float w = w1g[i * 64 + nt * 16 + c0] * 0.35355339059327373f;
      unsigned short hi = f2bf(w);
      B1[nt][i] = (g < 2) ? (short)hi : (short)f2bf(w - bfh2f(hi));
    }
  __syncthreads();   // only block-wide barrier (weight staging)

  unsigned short* hhi = &Hb[wv][0][0];
  unsigned short* hlo = &Hb[wv][1][0];
  const f4v z = {0.f, 0.f, 0.f, 0.f};

  const int node = blockIdx.x * 4 + wv;
  const int jb = row_start[node], je = row_start[node + 1];

  float nacc[16];
#pragma unroll
  for (int k = 0; k < 16; ++k) nacc[k] = 0.f;

  for (int base = jb; base < je; base += 16) {
    const int nvalid = je - base;
    // ---- prefetch per-edge data
    s8v A1 = {0, 0, 0, 0, 0, 0, 0, 0};
    int srcv[4];
    float4 yv[4];
    bool val[4];
    if constexpr (MAT) {
      if (c0 < nvalid)
        A1 = *(const s8v*)(esc_hl + (size_t)(base + c0) * 16 + (size_t)(g & 1) * 8);
#pragma unroll
      for (int i = 0; i < 4; ++i) {
        int s = g * 4 + i;
        val[i] = (s < nvalid);
        srcv[i] = 0; yv[i] = make_float4(0.f, 0.f, 0.f, 0.f);
        if (val[i]) { srcv[i] = src_s[base + s]; yv[i] = y_s[base + s]; }
      }
    } else {
      if (c0 < nvalid) {
        int eid = eidx[base + c0];
        const float4* p = (const float4*)(esc + (size_t)eid * 8);
        float4 a = p[0], b = p[1];
        float e8[8] = {a.x, a.y, a.z, a.w, b.x, b.y, b.z, b.w};
#pragma unroll
        for (int j = 0; j < 8; ++j) {
          unsigned short h, l;
          split_rtz(e8[j], h, l);
          A1[j] = (g & 1) ? (short)l : (short)h;
        }
      }
#pragma unroll
      for (int i = 0; i < 4; ++i) {
        int s = g * 4 + i;
        val[i] = (s < nvalid);
        srcv[i] = 0; yv[i] = make_float4(0.f, 0.f, 0.f, 0.f);
        if (val[i]) {
          int eid = eidx[base + s];
          srcv[i] = esrc[eid];
          yv[i] = *(const float4*)(eattr + (size_t)eid * 4);
        }
      }
    }
    // ---- stage 1: h1 = ssp(es @ W1s); pad rows skipped (stale values never consumed)
#pragma unroll
    for (int nt = 0; nt < 4; ++nt) {
      f4v acc = __builtin_amdgcn_mfma_f32_16x16x32_bf16(A1, B1[nt], z, 0, 0, 0);
#pragma unroll
      for (int i = 0; i < 4; ++i) {
        int r = g * 4 + i;
        if (r < nvalid) {
          float hv = sspf(acc[i]);
          unsigned short h, l;
          split_rtz(hv, h, l);
          hhi[r * 64 + swz(r, nt * 16 + c0)] = h;
          hlo[r * 64 + swz(r, nt * 16 + c0)] = l;
        }
      }
    }
    // ---- stage 2: h2 = ssp(h1 @ W2s) (per-wave in-order DS; frags loaded before overwrite)
    s8v A2ah = *(const s8v*)&hhi[c0 * 64 + swz(c0, 8 * g)];
    s8v A2bh = *(const s8v*)&hhi[c0 * 64 + swz(c0, 32 + 8 * g)];
    s8v A2al = *(const s8v*)&hlo[c0 * 64 + swz(c0, 8 * g)];
    s8v A2bl = *(const s8v*)&hlo[c0 * 64 + swz(c0, 32 + 8 * g)];
#pragma unroll
    for (int nt = 0; nt < 4; ++nt) {
      s8v Ba = *(const s8v*)&W2T[(nt * 16 + c0) * 64 + swz(c0, 8 * g)];
      s8v Bb = *(const s8v*)&W2T[(nt * 16 + c0) * 64 + swz(c0, 32 + 8 * g)];
      f4v acc = __builtin_amdgcn_mfma_f32_16x16x32_bf16(A2ah, Ba, z, 0, 0, 0);
      acc = __builtin_amdgcn_mfma_f32_16x16x32_bf16(A2bh, Bb, acc, 0, 0, 0);
      acc = __builtin_amdgcn_mfma_f32_16x16x32_bf16(A2al, Ba, acc, 0, 0, 0);
      acc = __builtin_amdgcn_mfma_f32_16x16x32_bf16(A2bl, Bb, acc, 0, 0, 0);
#pragma unroll
      for (int i = 0; i < 4; ++i) {
        int r = g * 4 + i;
        if (r < nvalid) {
          float hv = sspf(acc[i]);
          unsigned short h, l;
          split_rtz(hv, h, l);
          hhi[r * 64 + swz(r, nt * 16 + c0)] = h;
          hlo[r * 64 + swz(r, nt * 16 + c0)] = l;
        }
      }
    }
    // ---- s1v1 row loads before stage 3 (latency hides under MFMAs)
    float4 pr0[4], pr1[4];
#pragma unroll
    for (int i = 0; i < 4; ++i) {
      if (val[i]) {
        const float* svp = s1v1 + (size_t)srcv[i] * 128 + c0 * 8;
        pr0[i] = *(const float4*)svp;
        pr1[i] = *(const float4*)(svp + 4);
      } else {
        pr0[i] = make_float4(0.f, 0.f, 0.f, 0.f);
        pr1[i] = make_float4(0.f, 0.f, 0.f, 0.f);
      }
    }
    // ---- stage 3: w = h2 @ W3s
    s8v A3ah = *(const s8v*)&hhi[c0 * 64 + swz(c0, 8 * g)];
    s8v A3bh = *(const s8v*)&hhi[c0 * 64 + swz(c0, 32 + 8 * g)];
    s8v A3al = *(const s8v*)&hlo[c0 * 64 + swz(c0, 8 * g)];
    s8v A3bl = *(const s8v*)&hlo[c0 * 64 + swz(c0, 32 + 8 * g)];
    f4v acc3[8];
#pragma unroll
    for (int nt = 0; nt < 8; ++nt) {
      s8v Ba = *(const s8v*)&W3T[(nt * 16 + c0) * 64 + swz(c0, 8 * g)];
      s8v Bb = *(const s8v*)&W3T[(nt * 16 + c0) * 64 + swz(c0, 32 + 8 * g)];
      acc3[nt] = __builtin_amdgcn_mfma_f32_16x16x32_bf16(A3ah, Ba, z, 0, 0, 0);
      acc3[nt] = __builtin_amdgcn_mfma_f32_16x16x32_bf16(A3bh, Bb, acc3[nt], 0, 0, 0);
      acc3[nt] = __builtin_amdgcn_mfma_f32_16x16x32_bf16(A3al, Ba, acc3[nt], 0, 0, 0);
      acc3[nt] = __builtin_amdgcn_mfma_f32_16x16x32_bf16(A3bl, Bb, acc3[nt], 0, 0, 0);
    }
    // ---- epilogue: accumulate per-lane partials (reduce deferred to end of node)
#pragma unroll
    for (int i = 0; i < 4; ++i) {
      if (val[i]) {
        float w0 = acc3[0][i], w1_ = acc3[1][i], w2_ = acc3[2][i], w3_ = acc3[3][i];
        float w4_ = acc3[4][i], w5_ = acc3[5][i], w6_ = acc3[6][i], w7_ = acc3[7][i];
        float4 y = yv[i];
        float sA = pr0[i].x, sB = pr0[i].y;
        float vA0 = pr0[i].z, vA1 = pr0[i].w, vA2 = pr1[i].x;
        float vB0 = pr1[i].y, vB1 = pr1[i].z, vB2 = pr1[i].w;
        nacc[0] += w0 * sA * y.x;
        nacc[1] += w1_ * sB * y.x;
        nacc[2] += w6_ * (vA0 * y.y + vA1 * y.z + vA2 * y.w);
        nacc[3] += w7_ * (vB0 * y.y + vB1 * y.z + vB2 * y.w);
        nacc[4] += w2_ * sA * y.y;  nacc[5] += w2_ * sA * y.z;  nacc[6] += w2_ * sA * y.w;
        nacc[7] += w3_ * sB * y.y;  nacc[8] += w3_ * sB * y.z;  nacc[9] += w3_ * sB * y.w;
        nacc[10] += w4_ * vA0 * y.x; nacc[11] += w4_ * vA1 * y.x; nacc[12] += w4_ * vA2 * y.x;
        nacc[13] += w5_ * vB0 * y.x; nacc[14] += w5_ * vB1 * y.x; nacc[15] += w5_ * vB2 * y.x;
      }
    }
  }
  // ---- one cross-lane reduce per node
#pragma unroll
  for (int k = 0; k < 16; ++k) {
    float v = nacc[k];
    v += __shfl_xor(v, 16, 64);
    v += __shfl_xor(v, 32, 64);
    nacc[k] = v;
  }
  if (g == 0) {
    float* ad = agg + (size_t)node * 256;
    ad[c0] = nacc[0];
    ad[16 + c0] = nacc[1];
    ad[32 + c0] = nacc[2];
    ad[48 + c0] = nacc[3];
#pragma unroll
    for (int c = 0; c < 3; ++c) {
      ad[64 + 3 * c0 + c]  = nacc[4 + c];
      ad[112 + 3 * c0 + c] = nacc[7 + c];
      ad[160 + 3 * c0 + c] = nacc[10 + c];
      ad[208 + 3 * c0 + c] = nacc[13 + c];
    }
  }
}

// ---------------- node_post: lin2 + self-connection + gate + residual ----------------
__global__ __launch_bounds__(256) void k_node_post(
    const float* __restrict__ x, const float* __restrict__ attr, const float* __restrict__ agg,
    const float* __restrict__ l2s, const float* __restrict__ l2v,
    const float* __restrict__ scs, const float* __restrict__ scv,
    float* __restrict__ out)
{
  __shared__ float xa[4][4][136];
  __shared__ float ag[4][4][256];
  const int l = threadIdx.x & 63, wv = threadIdx.x >> 6;
  const int n0 = blockIdx.x * 16 + wv * 4;
#pragma unroll
  for (int b = 0; b < 4; ++b) {
    int nd = n0 + b;
    xa[wv][b][l] = x[(size_t)nd * 128 + l];
    xa[wv][b][64 + l] = x[(size_t)nd * 128 + 64 + l];
    if (l < 8) xa[wv][b][128 + l] = attr[nd * 8 + l];
#pragma unroll
    for (int q = 0; q < 4; ++q) ag[wv][b][q * 64 + l] = agg[(size_t)nd * 256 + q * 64 + l];
  }
  float attr_r[4][8];
#pragma unroll
  for (int b = 0; b < 4; ++b)
#pragma unroll
    for (int a = 0; a < 8; ++a) attr_r[b][a] = xa[wv][b][128 + a];

  const int w1 = l / 3, c1 = l - 3 * w1;
  const int f2 = 64 + l;
  const int w2r = f2 / 3, c2r = f2 - 3 * w2r;
  const int w2 = (l < 32) ? w2r : 0, c2 = (l < 32) ? c2r : 0;

  float acc[4] = {0.f, 0.f, 0.f, 0.f}, sa[4] = {0.f, 0.f, 0.f, 0.f};
  float av1[4] = {0.f, 0.f, 0.f, 0.f}, sv1[4] = {0.f, 0.f, 0.f, 0.f};
  float av2[4] = {0.f, 0.f, 0.f, 0.f}, sv2[4] = {0.f, 0.f, 0.f, 0.f};

#pragma unroll 8
  for (int u = 0; u < 64; ++u) {
    float wl = l2s[u * 64 + l];
#pragma unroll
    for (int b = 0; b < 4; ++b) acc[b] += ag[wv][b][u] * wl;
  }
#pragma unroll 4
  for (int u = 0; u < 64; ++u) {
    float wla = l2v[u * 32 + w1];
    float wlb = l2v[u * 32 + w2];
#pragma unroll
    for (int b = 0; b < 4; ++b) {
      av1[b] += ag[wv][b][64 + 3 * u + c1] * wla;
      av2[b] += ag[wv][b][64 + 3 * u + c2] * wlb;
    }
  }
  for (int u = 0; u < 32; ++u) {
    float sb[4];
#pragma unroll
    for (int b = 0; b < 4; ++b) sb[b] = xa[wv][b][u];
#pragma unroll
    for (int a = 0; a < 8; ++a) {
      float wl = scs[(u * 8 + a) * 64 + l];
#pragma unroll
      for (int b = 0; b < 4; ++b) sa[b] += sb[b] * attr_r[b][a] * wl;
    }
  }
  for (int u = 0; u < 32; ++u) {
    float vb1[4], vb2[4];
#pragma unroll
    for (int b = 0; b < 4; ++b) {
      vb1[b] = xa[wv][b][32 + 3 * u + c1];
      vb2[b] = xa[wv][b][32 + 3 * u + c2];
    }
#pragma unroll
    for (int a = 0; a < 8; ++a) {
      float wla = scv[(u * 8 + a) * 32 + w1];
      float wlb = scv[(u * 8 + a) * 32 + w2];
#pragma unroll
      for (int b = 0; b < 4; ++b) {
        sv1[b] += vb1[b] * attr_r[b][a] * wla;
        sv2[b] += vb2[b] * attr_r[b][a] * wlb;
      }
    }
  }

#pragma unroll
  for (int b = 0; b < 4; ++b) {
    float outs = acc[b] * 0.03125f + sa[b] * 0.0625f;
    float gss = sspf(outs);
    float ov1 = av1[b] * 0.03125f + sv1[b] * 0.0625f;
    float ov2 = av2[b] * 0.03125f + sv2[b] * 0.0625f;
    float gate1 = __shfl(gss, 32 + w1, 64);
    float gate2 = __shfl(gss, 32 + w2, 64);
    float* o = out + (size_t)(n0 + b) * 128;
    if (l < 32) o[l] = xa[wv][b][l] + gss;
    o[32 + l] = xa[wv][b][32 + l] + ov1 * gate1;
    if (l < 32) o[96 + l] = xa[wv][b][96 + l] + ov2 * gate2;
  }
}

extern "C" void kernel_launch(void* const* d_in, const int* in_sizes, int n_in,
                              void* d_out, int out_size, void* d_ws, size_t ws_size,
                              hipStream_t stream) {
  const float* node_input = (const float*)d_in[0];
  const float* node_attr  = (const float*)d_in[1];
  const int*   esrc  = (const int*)d_in[2];
  const int*   edst  = (const int*)d_in[3];
  const float* eattr = (const float*)d_in[4];
  const float* escal = (const float*)d_in[5];
  const float* l1s = (const float*)d_in[6];
  const float* l1v = (const float*)d_in[7];
  const float* w1  = (const float*)d_in[8];
  const float* w2  = (const float*)d_in[9];
  const float* w3  = (const float*)d_in[10];
  const float* l2s = (const float*)d_in[11];
  const float* l2v = (const float*)d_in[12];
  const float* scs = (const float*)d_in[13];
  const float* scv = (const float*)d_in[14];
  float* out  = (float*)d_out;

  char* p = (char*)d_ws;
  float* s1v1 = (float*)p;                 p += (size_t)N_NODES * 128 * 4;
  float* agg  = (float*)p;                 p += (size_t)N_NODES * 256 * 4;
  int* eidx   = (int*)p;                   p += (size_t)N_EDGES * 4;
  unsigned short* esc_hl = (unsigned short*)p;  p += (size_t)N_EDGES * 16 * 2;
  float4* y_s = (float4*)p;                p += (size_t)N_EDGES * 16;
  int* src_s  = (int*)p;                   p += (size_t)N_EDGES * 4;
  size_t need_mat = (size_t)(p - (char*)d_ws) + (size_t)(N_NODES * 2 + 1) * 4;
  char* tail = ((size_t)ws_size >= need_mat) ? p : (char*)(eidx + N_EDGES);
  int* counts    = (int*)tail;
  int* row_start = counts + N_NODES;
  int* cursor    = row_start + N_NODES + 1;
  const bool use_mat = ((size_t)ws_size >= need_mat);

  (void)hipMemsetAsync(counts, 0, (size_t)N_NODES * sizeof(int), stream);
  k_hist<<<(N_EDGES + 255) / 256, 256, 0, stream>>>(edst, counts);
  k_scan<<<1, SCAN_T, 0, stream>>>(counts, row_start, cursor);
  k_scatter<<<(N_EDGES + 255) / 256, 256, 0, stream>>>(edst, cursor, eidx);
  if (use_mat)
    k_sortmat<<<(N_NODES * 64 + 255) / 256, 256, 0, stream>>>(row_start, eidx,
        esrc, escal, eattr, esc_hl, y_s, src_s);
  else
    k_sortseg<<<(N_NODES * 64 + 255) / 256, 256, 0, stream>>>(row_start, eidx);

  for (int layer = 0; layer < 3; ++layer) {
    const float* xin = (layer == 0) ? node_input : (const float*)out;
    k_node_pre<<<N_NODES * 128 / 256, 256, 0, stream>>>(
        xin, l1s + layer * 1024, l1v + layer * 1024, s1v1);
    if (use_mat)
      k_edge_agg<1><<<N_NODES / 4, 256, 0, stream>>>(escal, esrc, eattr, esc_hl, src_s, y_s,
          s1v1, row_start, eidx, w1 + layer * 512, w2 + layer * 4096, w3 + layer * 8192, agg);
    else
      k_edge_agg<0><<<N_NODES / 4, 256, 0, stream>>>(escal, esrc, eattr, esc_hl, src_s, y_s,
          s1v1, row_start, eidx, w1 + layer * 512, w2 + layer * 4096, w3 + layer * 8192, agg);
    k_node_post<<<N_NODES / 16, 256, 0, stream>>>(xin, node_attr, agg,
        l2s + layer * 4096, l2v + layer * 2048, scs + layer * 16384, scv + layer * 8192, out);
  }
}

// Round 12
// 1768.234 us; speedup vs baseline: 1.3018x; 1.2432x over previous
//
#include <hip/hip_runtime.h>
#include <math.h>

#define N_NODES 30000
#define N_EDGES 480000

typedef __attribute__((ext_vector_type(8))) short s8v;   // 8 x bf16 (as i16 bits)
typedef __attribute__((ext_vector_type(4))) float f4v;

__device__ inline unsigned short f2bf(float f) {  // RNE (weights, staged once)
  union { float f; unsigned u; } v; v.f = f;
  return (unsigned short)((v.u + 0x7fffu + ((v.u >> 16) & 1u)) >> 16);
}
__device__ inline float bfh2f(unsigned short h) {
  union { unsigned u; float f; } v; v.u = (unsigned)h << 16; return v.f;
}
// cheap RTZ hi/lo split: hi+lo captures 16 mantissa bits (err ~2^-16 rel), 4 VALU ops
__device__ inline void split_rtz(float x, unsigned short& hi, unsigned short& lo) {
  unsigned u = __float_as_uint(x);
  hi = (unsigned short)(u >> 16);
  float hf = __uint_as_float(u & 0xffff0000u);
  lo = (unsigned short)(__float_as_uint(x - hf) >> 16);
}
// fast softplus(x) - log2: native exp/log (v_exp_f32/v_log_f32), no branches
__device__ inline float sspf(float x) {
  float t = __expf(-fabsf(x));
  return fmaxf(x, 0.f) + __logf(1.f + t) - 0.69314718055994531f;
}

// ---------------- CSR build (once per launch; edge_dst identical across layers) ----------------
__global__ __launch_bounds__(256) void k_hist(const int* __restrict__ edst, int* __restrict__ counts) {
  int e = blockIdx.x * 256 + threadIdx.x;
  if (e < N_EDGES) atomicAdd(&counts[edst[e]], 1);
}

#define SCAN_T 1024
#define NPER 30
__global__ __launch_bounds__(1024) void k_scan(const int* __restrict__ counts,
                                               int* __restrict__ row_start, int* __restrict__ cursor) {
  __shared__ int part[SCAN_T];
  int t = threadIdx.x;
  int base = t * NPER;
  int local[NPER];
  int s = 0;
#pragma unroll
  for (int j = 0; j < NPER; ++j) {
    int idx = base + j;
    int c = (idx < N_NODES) ? counts[idx] : 0;
    local[j] = s;
    s += c;
  }
  part[t] = s;
  __syncthreads();
  for (int off = 1; off < SCAN_T; off <<= 1) {
    int v = (t >= off) ? part[t - off] : 0;
    __syncthreads();
    part[t] += v;
    __syncthreads();
  }
  int pre = (t == 0) ? 0 : part[t - 1];
#pragma unroll
  for (int j = 0; j < NPER; ++j) {
    int idx = base + j;
    if (idx < N_NODES) {
      int v = pre + local[j];
      row_start[idx] = v;
      cursor[idx] = v;
    }
  }
  if (t == SCAN_T - 1) row_start[N_NODES] = pre + s;
}

__global__ __launch_bounds__(256) void k_scatter(const int* __restrict__ edst,
                                                 int* __restrict__ cursor, int* __restrict__ eidx) {
  int e = blockIdx.x * 256 + threadIdx.x;
  if (e < N_EDGES) {
    int pos = atomicAdd(&cursor[edst[e]], 1);
    eidx[pos] = e;
  }
}

// fallback (no-MAT): sort each segment for determinism
__global__ __launch_bounds__(256) void k_sortseg(const int* __restrict__ row_start, int* __restrict__ eidx) {
  int wid = (blockIdx.x * 256 + threadIdx.x) >> 6;
  int lane = threadIdx.x & 63;
  if (wid >= N_NODES) return;
  int jb = row_start[wid], je = row_start[wid + 1];
  int deg = je - jb;
  if (deg <= 1) return;
  if (deg <= 64) {
    int key = (lane < deg) ? eidx[jb + lane] : 0x7fffffff;
#pragma unroll
    for (int k = 2; k <= 64; k <<= 1)
      for (int j = k >> 1; j > 0; j >>= 1) {
        int other = __shfl_xor(key, j, 64);
        bool asc = ((lane & k) == 0);
        bool upper = ((lane & j) != 0);
        key = (upper == asc) ? max(key, other) : min(key, other);
      }
    if (lane < deg) eidx[jb + lane] = key;
  } else if (lane == 0) {
    for (int i = jb + 1; i < je; ++i) {
      int v = eidx[i];
      int j = i - 1;
      while (j >= jb && eidx[j] > v) { eidx[j + 1] = eidx[j]; --j; }
      eidx[j + 1] = v;
    }
  }
}

// ---------------- fused sort + materialize (1 wave = 1 dst node, once per launch) ------------
__global__ __launch_bounds__(256) void k_sortmat(const int* __restrict__ row_start, int* __restrict__ eidx,
    const int* __restrict__ esrc, const float* __restrict__ esc, const float* __restrict__ eattr,
    unsigned short* __restrict__ esc_hl, float4* __restrict__ y_s, int* __restrict__ src_s) {
  int wid = (blockIdx.x * 256 + threadIdx.x) >> 6;
  int lane = threadIdx.x & 63;
  if (wid >= N_NODES) return;
  int jb = row_start[wid], je = row_start[wid + 1];
  int deg = je - jb;
  if (deg <= 0) return;
  if (deg <= 64) {
    int key = (lane < deg) ? eidx[jb + lane] : 0x7fffffff;
#pragma unroll
    for (int k = 2; k <= 64; k <<= 1)
      for (int j = k >> 1; j > 0; j >>= 1) {
        int other = __shfl_xor(key, j, 64);
        bool asc = ((lane & k) == 0);
        bool upper = ((lane & j) != 0);
        key = (upper == asc) ? max(key, other) : min(key, other);
      }
    if (lane < deg) {
      int p = jb + lane, e = key;
      src_s[p] = esrc[e];
      y_s[p] = *(const float4*)(eattr + (size_t)e * 4);
      const float4* q = (const float4*)(esc + (size_t)e * 8);
      float4 a = q[0], b = q[1];
      float e8[8] = {a.x, a.y, a.z, a.w, b.x, b.y, b.z, b.w};
      s8v hi, lo;
#pragma unroll
      for (int j = 0; j < 8; ++j) {
        unsigned short h, l;
        split_rtz(e8[j], h, l);
        hi[j] = (short)h; lo[j] = (short)l;
      }
      *(s8v*)(esc_hl + (size_t)p * 16) = hi;
      *(s8v*)(esc_hl + (size_t)p * 16 + 8) = lo;
    }
  } else {
    if (lane == 0) {  // rare fallback
      for (int i = jb + 1; i < je; ++i) {
        int v = eidx[i];
        int j = i - 1;
        while (j >= jb && eidx[j] > v) { eidx[j + 1] = eidx[j]; --j; }
        eidx[j + 1] = v;
      }
    }
    for (int p = jb + lane; p < je; p += 64) {
      int e = eidx[p];
      src_s[p] = esrc[e];
      y_s[p] = *(const float4*)(eattr + (size_t)e * 4);
      const float4* q = (const float4*)(esc + (size_t)e * 8);
      float4 a = q[0], b = q[1];
      float e8[8] = {a.x, a.y, a.z, a.w, b.x, b.y, b.z, b.w};
      s8v hi, lo;
#pragma unroll
      for (int j = 0; j < 8; ++j) {
        unsigned short h, l;
        split_rtz(e8[j], h, l);
        hi[j] = (short)h; lo[j] = (short)l;
      }
      *(s8v*)(esc_hl + (size_t)p * 16) = hi;
      *(s8v*)(esc_hl + (size_t)p * 16 + 8) = lo;
    }
  }
}

// ---------------- node_pre: low-divergence compute, permuted store into interleaved layout -------
__global__ __launch_bounds__(256) void k_node_pre(const float* __restrict__ x,
    const float* __restrict__ l1s, const float* __restrict__ l1v,
    float* __restrict__ s1v1)
{
  int t = blockIdx.x * 256 + threadIdx.x;
  int node = t >> 7, j = t & 127;
  const float* xr = x + (size_t)node * 128;
  float acc = 0.f;
  int addr;
  if (j < 32) {
    int m = j;
#pragma unroll
    for (int u = 0; u < 32; ++u) acc += xr[u] * l1s[u * 32 + m];
    addr = (m & 15) * 8 + (m >> 4);
  } else {
    int jj = j - 32, m = jj / 3, c = jj - 3 * m;
#pragma unroll
    for (int u = 0; u < 32; ++u) acc += xr[32 + u * 3 + c] * l1v[u * 32 + m];
    addr = (m & 15) * 8 + 2 + (m >> 4) * 3 + c;
  }
  s1v1[(size_t)node * 128 + addr] = acc * 0.17677669529663689f;
}

// ---------------- fused edge MLP + per-node aggregation (1 wave = 1 dst node, no atomics) --------
// R12 = R8's exact proven structure (stride-72 padded LDS, per-tile B LDS reads, (256,3))
// + R9's benign pad-row skip only. R10/R11's stride-64 XOR variant spilled to scratch — reverted.
template<int MAT>
__global__ __launch_bounds__(256, 3) void k_edge_agg(
    const float* __restrict__ esc, const int* __restrict__ esrc, const float* __restrict__ eattr,
    const unsigned short* __restrict__ esc_hl, const int* __restrict__ src_s, const float4* __restrict__ y_s,
    const float* __restrict__ s1v1, const int* __restrict__ row_start, const int* __restrict__ eidx,
    const float* __restrict__ w1g, const float* __restrict__ w2g, const float* __restrict__ w3g,
    float* __restrict__ agg)
{
  __shared__ __attribute__((aligned(16))) unsigned short W2T[64 * 72];
  __shared__ __attribute__((aligned(16))) unsigned short W3T[128 * 72];
  __shared__ __attribute__((aligned(16))) unsigned short Hb[4][2][16 * 72];

  const int tid = threadIdx.x, lane = tid & 63, wv = tid >> 6;
  const int c0 = lane & 15, g = lane >> 4;

  for (int idx = tid; idx < 64 * 64; idx += 256) {
    int k = idx >> 6, n2 = idx & 63;
    W2T[n2 * 72 + k] = f2bf(w2g[idx] * 0.125f);      // exact pow2 fold
  }
  for (int idx = tid; idx < 64 * 128; idx += 256) {
    int k = idx >> 7, n2 = idx & 127;
    W3T[n2 * 72 + k] = f2bf(w3g[idx] * 0.125f);      // exact pow2 fold
  }
  // B1 carries 1/sqrt(8): hi/lo split of the scaled weight
  s8v B1[4];
#pragma unroll
  for (int nt = 0; nt < 4; ++nt)
#pragma unroll
    for (int i = 0; i < 8; ++i) {
      float w = w1g[i * 64 + nt * 16 + c0] * 0.35355339059327373f;
      unsigned short hi = f2bf(w);
      B1[nt][i] = (g < 2) ? (short)hi : (short)f2bf(w - bfh2f(hi));
    }
  __syncthreads();   // only block-wide barrier (weight staging)

  unsigned short* hhi = &Hb[wv][0][0];
  unsigned short* hlo = &Hb[wv][1][0];
  const f4v z = {0.f, 0.f, 0.f, 0.f};

  const int node = blockIdx.x * 4 + wv;
  const int jb = row_start[node], je = row_start[node + 1];

  float nacc[16];
#pragma unroll
  for (int k = 0; k < 16; ++k) nacc[k] = 0.f;

  for (int base = jb; base < je; base += 16) {
    const int nvalid = je - base;
    // ---- prefetch per-edge data
    s8v A1 = {0, 0, 0, 0, 0, 0, 0, 0};
    int srcv[4];
    float4 yv[4];
    bool val[4];
    if constexpr (MAT) {
      if (c0 < nvalid)
        A1 = *(const s8v*)(esc_hl + (size_t)(base + c0) * 16 + (size_t)(g & 1) * 8);
#pragma unroll
      for (int i = 0; i < 4; ++i) {
        int s = g * 4 + i;
        val[i] = (s < nvalid);
        srcv[i] = 0; yv[i] = make_float4(0.f, 0.f, 0.f, 0.f);
        if (val[i]) { srcv[i] = src_s[base + s]; yv[i] = y_s[base + s]; }
      }
    } else {
      if (c0 < nvalid) {
        int eid = eidx[base + c0];
        const float4* p = (const float4*)(esc + (size_t)eid * 8);
        float4 a = p[0], b = p[1];
        float e8[8] = {a.x, a.y, a.z, a.w, b.x, b.y, b.z, b.w};
#pragma unroll
        for (int j = 0; j < 8; ++j) {
          unsigned short h, l;
          split_rtz(e8[j], h, l);
          A1[j] = (g & 1) ? (short)l : (short)h;
        }
      }
#pragma unroll
      for (int i = 0; i < 4; ++i) {
        int s = g * 4 + i;
        val[i] = (s < nvalid);
        srcv[i] = 0; yv[i] = make_float4(0.f, 0.f, 0.f, 0.f);
        if (val[i]) {
          int eid = eidx[base + s];
          srcv[i] = esrc[eid];
          yv[i] = *(const float4*)(eattr + (size_t)eid * 4);
        }
      }
    }
    // ---- stage 1: h1 = ssp(es @ W1s); pad rows skipped (stale values never consumed)
#pragma unroll
    for (int nt = 0; nt < 4; ++nt) {
      f4v acc = __builtin_amdgcn_mfma_f32_16x16x32_bf16(A1, B1[nt], z, 0, 0, 0);
#pragma unroll
      for (int i = 0; i < 4; ++i) {
        int r = g * 4 + i;
        if (r < nvalid) {
          float hv = sspf(acc[i]);
          unsigned short h, l;
          split_rtz(hv, h, l);
          hhi[r * 72 + nt * 16 + c0] = h;
          hlo[r * 72 + nt * 16 + c0] = l;
        }
      }
    }
    // ---- stage 2: h2 = ssp(h1 @ W2s) (per-wave in-order DS; frags loaded before overwrite)
    s8v A2ah = *(const s8v*)&hhi[c0 * 72 + 8 * g];
    s8v A2bh = *(const s8v*)&hhi[c0 * 72 + 32 + 8 * g];
    s8v A2al = *(const s8v*)&hlo[c0 * 72 + 8 * g];
    s8v A2bl = *(const s8v*)&hlo[c0 * 72 + 32 + 8 * g];
#pragma unroll
    for (int nt = 0; nt < 4; ++nt) {
      s8v Ba = *(const s8v*)&W2T[(nt * 16 + c0) * 72 + 8 * g];
      s8v Bb = *(const s8v*)&W2T[(nt * 16 + c0) * 72 + 32 + 8 * g];
      f4v acc = __builtin_amdgcn_mfma_f32_16x16x32_bf16(A2ah, Ba, z, 0, 0, 0);
      acc = __builtin_amdgcn_mfma_f32_16x16x32_bf16(A2bh, Bb, acc, 0, 0, 0);
      acc = __builtin_amdgcn_mfma_f32_16x16x32_bf16(A2al, Ba, acc, 0, 0, 0);
      acc = __builtin_amdgcn_mfma_f32_16x16x32_bf16(A2bl, Bb, acc, 0, 0, 0);
#pragma unroll
      for (int i = 0; i < 4; ++i) {
        int r = g * 4 + i;
        if (r < nvalid) {
          float hv = sspf(acc[i]);
          unsigned short h, l;
          split_rtz(hv, h, l);
          hhi[r * 72 + nt * 16 + c0] = h;
          hlo[r * 72 + nt * 16 + c0] = l;
        }
      }
    }
    // ---- s1v1 row loads before stage 3 (latency hides under MFMAs)
    float4 pr0[4], pr1[4];
#pragma unroll
    for (int i = 0; i < 4; ++i) {
      if (val[i]) {
        const float* svp = s1v1 + (size_t)srcv[i] * 128 + c0 * 8;
        pr0[i] = *(const float4*)svp;
        pr1[i] = *(const float4*)(svp + 4);
      } else {
        pr0[i] = make_float4(0.f, 0.f, 0.f, 0.f);
        pr1[i] = make_float4(0.f, 0.f, 0.f, 0.f);
      }
    }
    // ---- stage 3: w = h2 @ W3s
    s8v A3ah = *(const s8v*)&hhi[c0 * 72 + 8 * g];
    s8v A3bh = *(const s8v*)&hhi[c0 * 72 + 32 + 8 * g];
    s8v A3al = *(const s8v*)&hlo[c0 * 72 + 8 * g];
    s8v A3bl = *(const s8v*)&hlo[c0 * 72 + 32 + 8 * g];
    f4v acc3[8];
#pragma unroll
    for (int nt = 0; nt < 8; ++nt) {
      s8v Ba = *(const s8v*)&W3T[(nt * 16 + c0) * 72 + 8 * g];
      s8v Bb = *(const s8v*)&W3T[(nt * 16 + c0) * 72 + 32 + 8 * g];
      acc3[nt] = __builtin_amdgcn_mfma_f32_16x16x32_bf16(A3ah, Ba, z, 0, 0, 0);
      acc3[nt] = __builtin_amdgcn_mfma_f32_16x16x32_bf16(A3bh, Bb, acc3[nt], 0, 0, 0);
      acc3[nt] = __builtin_amdgcn_mfma_f32_16x16x32_bf16(A3al, Ba, acc3[nt], 0, 0, 0);
      acc3[nt] = __builtin_amdgcn_mfma_f32_16x16x32_bf16(A3bl, Bb, acc3[nt], 0, 0, 0);
    }
    // ---- epilogue: accumulate per-lane partials (reduce deferred to end of node)
#pragma unroll
    for (int i = 0; i < 4; ++i) {
      if (val[i]) {
        float w0 = acc3[0][i], w1_ = acc3[1][i], w2_ = acc3[2][i], w3_ = acc3[3][i];
        float w4_ = acc3[4][i], w5_ = acc3[5][i], w6_ = acc3[6][i], w7_ = acc3[7][i];
        float4 y = yv[i];
        float sA = pr0[i].x, sB = pr0[i].y;
        float vA0 = pr0[i].z, vA1 = pr0[i].w, vA2 = pr1[i].x;
        float vB0 = pr1[i].y, vB1 = pr1[i].z, vB2 = pr1[i].w;
        nacc[0] += w0 * sA * y.x;
        nacc[1] += w1_ * sB * y.x;
        nacc[2] += w6_ * (vA0 * y.y + vA1 * y.z + vA2 * y.w);
        nacc[3] += w7_ * (vB0 * y.y + vB1 * y.z + vB2 * y.w);
        nacc[4] += w2_ * sA * y.y;  nacc[5] += w2_ * sA * y.z;  nacc[6] += w2_ * sA * y.w;
        nacc[7] += w3_ * sB * y.y;  nacc[8] += w3_ * sB * y.z;  nacc[9] += w3_ * sB * y.w;
        nacc[10] += w4_ * vA0 * y.x; nacc[11] += w4_ * vA1 * y.x; nacc[12] += w4_ * vA2 * y.x;
        nacc[13] += w5_ * vB0 * y.x; nacc[14] += w5_ * vB1 * y.x; nacc[15] += w5_ * vB2 * y.x;
      }
    }
  }
  // ---- one cross-lane reduce per node
#pragma unroll
  for (int k = 0; k < 16; ++k) {
    float v = nacc[k];
    v += __shfl_xor(v, 16, 64);
    v += __shfl_xor(v, 32, 64);
    nacc[k] = v;
  }
  if (g == 0) {
    float* ad = agg + (size_t)node * 256;
    ad[c0] = nacc[0];
    ad[16 + c0] = nacc[1];
    ad[32 + c0] = nacc[2];
    ad[48 + c0] = nacc[3];
#pragma unroll
    for (int c = 0; c < 3; ++c) {
      ad[64 + 3 * c0 + c]  = nacc[4 + c];
      ad[112 + 3 * c0 + c] = nacc[7 + c];
      ad[160 + 3 * c0 + c] = nacc[10 + c];
      ad[208 + 3 * c0 + c] = nacc[13 + c];
    }
  }
}

// ---------------- node_post: lin2 + self-connection + gate + residual ----------------
__global__ __launch_bounds__(256) void k_node_post(
    const float* __restrict__ x, const float* __restrict__ attr, const float* __restrict__ agg,
    const float* __restrict__ l2s, const float* __restrict__ l2v,
    const float* __restrict__ scs, const float* __restrict__ scv,
    float* __restrict__ out)
{
  __shared__ float xa[4][4][136];
  __shared__ float ag[4][4][256];
  const int l = threadIdx.x & 63, wv = threadIdx.x >> 6;
  const int n0 = blockIdx.x * 16 + wv * 4;
#pragma unroll
  for (int b = 0; b < 4; ++b) {
    int nd = n0 + b;
    xa[wv][b][l] = x[(size_t)nd * 128 + l];
    xa[wv][b][64 + l] = x[(size_t)nd * 128 + 64 + l];
    if (l < 8) xa[wv][b][128 + l] = attr[nd * 8 + l];
#pragma unroll
    for (int q = 0; q < 4; ++q) ag[wv][b][q * 64 + l] = agg[(size_t)nd * 256 + q * 64 + l];
  }
  float attr_r[4][8];
#pragma unroll
  for (int b = 0; b < 4; ++b)
#pragma unroll
    for (int a = 0; a < 8; ++a) attr_r[b][a] = xa[wv][b][128 + a];

  const int w1 = l / 3, c1 = l - 3 * w1;
  const int f2 = 64 + l;
  const int w2r = f2 / 3, c2r = f2 - 3 * w2r;
  const int w2 = (l < 32) ? w2r : 0, c2 = (l < 32) ? c2r : 0;

  float acc[4] = {0.f, 0.f, 0.f, 0.f}, sa[4] = {0.f, 0.f, 0.f, 0.f};
  float av1[4] = {0.f, 0.f, 0.f, 0.f}, sv1[4] = {0.f, 0.f, 0.f, 0.f};
  float av2[4] = {0.f, 0.f, 0.f, 0.f}, sv2[4] = {0.f, 0.f, 0.f, 0.f};

#pragma unroll 8
  for (int u = 0; u < 64; ++u) {
    float wl = l2s[u * 64 + l];
#pragma unroll
    for (int b = 0; b < 4; ++b) acc[b] += ag[wv][b][u] * wl;
  }
#pragma unroll 4
  for (int u = 0; u < 64; ++u) {
    float wla = l2v[u * 32 + w1];
    float wlb = l2v[u * 32 + w2];
#pragma unroll
    for (int b = 0; b < 4; ++b) {
      av1[b] += ag[wv][b][64 + 3 * u + c1] * wla;
      av2[b] += ag[wv][b][64 + 3 * u + c2] * wlb;
    }
  }
  for (int u = 0; u < 32; ++u) {
    float sb[4];
#pragma unroll
    for (int b = 0; b < 4; ++b) sb[b] = xa[wv][b][u];
#pragma unroll
    for (int a = 0; a < 8; ++a) {
      float wl = scs[(u * 8 + a) * 64 + l];
#pragma unroll
      for (int b = 0; b < 4; ++b) sa[b] += sb[b] * attr_r[b][a] * wl;
    }
  }
  for (int u = 0; u < 32; ++u) {
    float vb1[4], vb2[4];
#pragma unroll
    for (int b = 0; b < 4; ++b) {
      vb1[b] = xa[wv][b][32 + 3 * u + c1];
      vb2[b] = xa[wv][b][32 + 3 * u + c2];
    }
#pragma unroll
    for (int a = 0; a < 8; ++a) {
      float wla = scv[(u * 8 + a) * 32 + w1];
      float wlb = scv[(u * 8 + a) * 32 + w2];
#pragma unroll
      for (int b = 0; b < 4; ++b) {
        sv1[b] += vb1[b] * attr_r[b][a] * wla;
        sv2[b] += vb2[b] * attr_r[b][a] * wlb;
      }
    }
  }

#pragma unroll
  for (int b = 0; b < 4; ++b) {
    float outs = acc[b] * 0.03125f + sa[b] * 0.0625f;
    float gss = sspf(outs);
    float ov1 = av1[b] * 0.03125f + sv1[b] * 0.0625f;
    float ov2 = av2[b] * 0.03125f + sv2[b] * 0.0625f;
    float gate1 = __shfl(gss, 32 + w1, 64);
    float gate2 = __shfl(gss, 32 + w2, 64);
    float* o = out + (size_t)(n0 + b) * 128;
    if (l < 32) o[l] = xa[wv][b][l] + gss;
    o[32 + l] = xa[wv][b][32 + l] + ov1 * gate1;
    if (l < 32) o[96 + l] = xa[wv][b][96 + l] + ov2 * gate2;
  }
}

extern "C" void kernel_launch(void* const* d_in, const int* in_sizes, int n_in,
                              void* d_out, int out_size, void* d_ws, size_t ws_size,
                              hipStream_t stream) {
  const float* node_input = (const float*)d_in[0];
  const float* node_attr  = (const float*)d_in[1];
  const int*   esrc  = (const int*)d_in[2];
  const int*   edst  = (const int*)d_in[3];
  const float* eattr = (const float*)d_in[4];
  const float* escal = (const float*)d_in[5];
  const float* l1s = (const float*)d_in[6];
  const float* l1v = (const float*)d_in[7];
  const float* w1  = (const float*)d_in[8];
  const float* w2  = (const float*)d_in[9];
  const float* w3  = (const float*)d_in[10];
  const float* l2s = (const float*)d_in[11];
  const float* l2v = (const float*)d_in[12];
  const float* scs = (const float*)d_in[13];
  const float* scv = (const float*)d_in[14];
  float* out  = (float*)d_out;

  char* p = (char*)d_ws;
  float* s1v1 = (float*)p;                 p += (size_t)N_NODES * 128 * 4;
  float* agg  = (float*)p;                 p += (size_t)N_NODES * 256 * 4;
  int* eidx   = (int*)p;                   p += (size_t)N_EDGES * 4;
  unsigned short* esc_hl = (unsigned short*)p;  p += (size_t)N_EDGES * 16 * 2;
  float4* y_s = (float4*)p;                p += (size_t)N_EDGES * 16;
  int* src_s  = (int*)p;                   p += (size_t)N_EDGES * 4;
  size_t need_mat = (size_t)(p - (char*)d_ws) + (size_t)(N_NODES * 2 + 1) * 4;
  char* tail = ((size_t)ws_size >= need_mat) ? p : (char*)(eidx + N_EDGES);
  int* counts    = (int*)tail;
  int* row_start = counts + N_NODES;
  int* cursor    = row_start + N_NODES + 1;
  const bool use_mat = ((size_t)ws_size >= need_mat);

  (void)hipMemsetAsync(counts, 0, (size_t)N_NODES * sizeof(int), stream);
  k_hist<<<(N_EDGES + 255) / 256, 256, 0, stream>>>(edst, counts);
  k_scan<<<1, SCAN_T, 0, stream>>>(counts, row_start, cursor);
  k_scatter<<<(N_EDGES + 255) / 256, 256, 0, stream>>>(edst, cursor, eidx);
  if (use_mat)
    k_sortmat<<<(N_NODES * 64 + 255) / 256, 256, 0, stream>>>(row_start, eidx,
        esrc, escal, eattr, esc_hl, y_s, src_s);
  else
    k_sortseg<<<(N_NODES * 64 + 255) / 256, 256, 0, stream>>>(row_start, eidx);

  for (int layer = 0; layer < 3; ++layer) {
    const float* xin = (layer == 0) ? node_input : (const float*)out;
    k_node_pre<<<N_NODES * 128 / 256, 256, 0, stream>>>(
        xin, l1s + layer * 1024, l1v + layer * 1024, s1v1);
    if (use_mat)
      k_edge_agg<1><<<N_NODES / 4, 256, 0, stream>>>(escal, esrc, eattr, esc_hl, src_s, y_s,
          s1v1, row_start, eidx, w1 + layer * 512, w2 + layer * 4096, w3 + layer * 8192, agg);
    else
      k_edge_agg<0><<<N_NODES / 4, 256, 0, stream>>>(escal, esrc, eattr, esc_hl, src_s, y_s,
          s1v1, row_start, eidx, w1 + layer * 512, w2 + layer * 4096, w3 + layer * 8192, agg);
    k_node_post<<<N_NODES / 16, 256, 0, stream>>>(xin, node_attr, agg,
        l2s + layer * 4096, l2v + layer * 2048, scs + layer * 16384, scv + layer * 8192, out);
  }
}

// Round 13
// 1191.957 us; speedup vs baseline: 1.9313x; 1.4835x over previous
//
#include <hip/hip_runtime.h>
#include <math.h>

#define N_NODES 30000
#define N_EDGES 480000

typedef __attribute__((ext_vector_type(8))) short s8v;   // 8 x bf16 (as i16 bits)
typedef __attribute__((ext_vector_type(4))) float f4v;

__device__ inline unsigned short f2bf(float f) {  // RNE (weights, staged once)
  union { float f; unsigned u; } v; v.f = f;
  return (unsigned short)((v.u + 0x7fffu + ((v.u >> 16) & 1u)) >> 16);
}
__device__ inline float bfh2f(unsigned short h) {
  union { unsigned u; float f; } v; v.u = (unsigned)h << 16; return v.f;
}
// cheap RTZ hi/lo split: hi+lo captures 16 mantissa bits (err ~2^-16 rel), 4 VALU ops
__device__ inline void split_rtz(float x, unsigned short& hi, unsigned short& lo) {
  unsigned u = __float_as_uint(x);
  hi = (unsigned short)(u >> 16);
  float hf = __uint_as_float(u & 0xffff0000u);
  lo = (unsigned short)(__float_as_uint(x - hf) >> 16);
}
// fast softplus(x) - log2: native exp/log (v_exp_f32/v_log_f32), no branches
__device__ inline float sspf(float x) {
  float t = __expf(-fabsf(x));
  return fmaxf(x, 0.f) + __logf(1.f + t) - 0.69314718055994531f;
}

// ---------------- CSR build (once per launch; edge_dst identical across layers) ----------------
__global__ __launch_bounds__(256) void k_hist(const int* __restrict__ edst, int* __restrict__ counts) {
  int e = blockIdx.x * 256 + threadIdx.x;
  if (e < N_EDGES) atomicAdd(&counts[edst[e]], 1);
}

#define SCAN_T 1024
#define NPER 30
__global__ __launch_bounds__(1024) void k_scan(const int* __restrict__ counts,
                                               int* __restrict__ row_start, int* __restrict__ cursor) {
  __shared__ int part[SCAN_T];
  int t = threadIdx.x;
  int base = t * NPER;
  int local[NPER];
  int s = 0;
#pragma unroll
  for (int j = 0; j < NPER; ++j) {
    int idx = base + j;
    int c = (idx < N_NODES) ? counts[idx] : 0;
    local[j] = s;
    s += c;
  }
  part[t] = s;
  __syncthreads();
  for (int off = 1; off < SCAN_T; off <<= 1) {
    int v = (t >= off) ? part[t - off] : 0;
    __syncthreads();
    part[t] += v;
    __syncthreads();
  }
  int pre = (t == 0) ? 0 : part[t - 1];
#pragma unroll
  for (int j = 0; j < NPER; ++j) {
    int idx = base + j;
    if (idx < N_NODES) {
      int v = pre + local[j];
      row_start[idx] = v;
      cursor[idx] = v;
    }
  }
  if (t == SCAN_T - 1) row_start[N_NODES] = pre + s;
}

__global__ __launch_bounds__(256) void k_scatter(const int* __restrict__ edst,
                                                 int* __restrict__ cursor, int* __restrict__ eidx) {
  int e = blockIdx.x * 256 + threadIdx.x;
  if (e < N_EDGES) {
    int pos = atomicAdd(&cursor[edst[e]], 1);
    eidx[pos] = e;
  }
}

// fallback (no-MAT): sort each segment for determinism
__global__ __launch_bounds__(256) void k_sortseg(const int* __restrict__ row_start, int* __restrict__ eidx) {
  int wid = (blockIdx.x * 256 + threadIdx.x) >> 6;
  int lane = threadIdx.x & 63;
  if (wid >= N_NODES) return;
  int jb = row_start[wid], je = row_start[wid + 1];
  int deg = je - jb;
  if (deg <= 1) return;
  if (deg <= 64) {
    int key = (lane < deg) ? eidx[jb + lane] : 0x7fffffff;
#pragma unroll
    for (int k = 2; k <= 64; k <<= 1)
      for (int j = k >> 1; j > 0; j >>= 1) {
        int other = __shfl_xor(key, j, 64);
        bool asc = ((lane & k) == 0);
        bool upper = ((lane & j) != 0);
        key = (upper == asc) ? max(key, other) : min(key, other);
      }
    if (lane < deg) eidx[jb + lane] = key;
  } else if (lane == 0) {
    for (int i = jb + 1; i < je; ++i) {
      int v = eidx[i];
      int j = i - 1;
      while (j >= jb && eidx[j] > v) { eidx[j + 1] = eidx[j]; --j; }
      eidx[j + 1] = v;
    }
  }
}

// ---------------- fused sort + materialize (1 wave = 1 dst node, once per launch) ------------
// sorts segment keys in-register (deterministic), then emits sorted per-edge data directly:
// esc_hl[pos]: [8 bf16-hi | 8 bf16-lo]; y_s[pos]=eattr; src_s[pos]=esrc.
__global__ __launch_bounds__(256) void k_sortmat(const int* __restrict__ row_start, int* __restrict__ eidx,
    const int* __restrict__ esrc, const float* __restrict__ esc, const float* __restrict__ eattr,
    unsigned short* __restrict__ esc_hl, float4* __restrict__ y_s, int* __restrict__ src_s) {
  int wid = (blockIdx.x * 256 + threadIdx.x) >> 6;
  int lane = threadIdx.x & 63;
  if (wid >= N_NODES) return;
  int jb = row_start[wid], je = row_start[wid + 1];
  int deg = je - jb;
  if (deg <= 0) return;
  if (deg <= 64) {
    int key = (lane < deg) ? eidx[jb + lane] : 0x7fffffff;
#pragma unroll
    for (int k = 2; k <= 64; k <<= 1)
      for (int j = k >> 1; j > 0; j >>= 1) {
        int other = __shfl_xor(key, j, 64);
        bool asc = ((lane & k) == 0);
        bool upper = ((lane & j) != 0);
        key = (upper == asc) ? max(key, other) : min(key, other);
      }
    if (lane < deg) {
      int p = jb + lane, e = key;
      src_s[p] = esrc[e];
      y_s[p] = *(const float4*)(eattr + (size_t)e * 4);
      const float4* q = (const float4*)(esc + (size_t)e * 8);
      float4 a = q[0], b = q[1];
      float e8[8] = {a.x, a.y, a.z, a.w, b.x, b.y, b.z, b.w};
      s8v hi, lo;
#pragma unroll
      for (int j = 0; j < 8; ++j) {
        unsigned short h, l;
        split_rtz(e8[j], h, l);
        hi[j] = (short)h; lo[j] = (short)l;
      }
      *(s8v*)(esc_hl + (size_t)p * 16) = hi;
      *(s8v*)(esc_hl + (size_t)p * 16 + 8) = lo;
    }
  } else {
    if (lane == 0) {  // rare fallback
      for (int i = jb + 1; i < je; ++i) {
        int v = eidx[i];
        int j = i - 1;
        while (j >= jb && eidx[j] > v) { eidx[j + 1] = eidx[j]; --j; }
        eidx[j + 1] = v;
      }
    }
    for (int p = jb + lane; p < je; p += 64) {
      int e = eidx[p];
      src_s[p] = esrc[e];
      y_s[p] = *(const float4*)(eattr + (size_t)e * 4);
      const float4* q = (const float4*)(esc + (size_t)e * 8);
      float4 a = q[0], b = q[1];
      float e8[8] = {a.x, a.y, a.z, a.w, b.x, b.y, b.z, b.w};
      s8v hi, lo;
#pragma unroll
      for (int j = 0; j < 8; ++j) {
        unsigned short h, l;
        split_rtz(e8[j], h, l);
        hi[j] = (short)h; lo[j] = (short)l;
      }
      *(s8v*)(esc_hl + (size_t)p * 16) = hi;
      *(s8v*)(esc_hl + (size_t)p * 16 + 8) = lo;
    }
  }
}

// ---------------- node_pre: low-divergence compute, permuted store into interleaved layout -------
// s1v1 row: slot(0..15)*8 + {0:s1[slot],1:s1[slot+16],2+c:v1[slot][c],5+c:v1[slot+16][c]}
__global__ __launch_bounds__(256) void k_node_pre(const float* __restrict__ x,
    const float* __restrict__ l1s, const float* __restrict__ l1v,
    float* __restrict__ s1v1)
{
  int t = blockIdx.x * 256 + threadIdx.x;
  int node = t >> 7, j = t & 127;
  const float* xr = x + (size_t)node * 128;
  float acc = 0.f;
  int addr;
  if (j < 32) {
    int m = j;
#pragma unroll
    for (int u = 0; u < 32; ++u) acc += xr[u] * l1s[u * 32 + m];
    addr = (m & 15) * 8 + (m >> 4);
  } else {
    int jj = j - 32, m = jj / 3, c = jj - 3 * m;
#pragma unroll
    for (int u = 0; u < 32; ++u) acc += xr[32 + u * 3 + c] * l1v[u * 32 + m];
    addr = (m & 15) * 8 + 2 + (m >> 4) * 3 + c;
  }
  s1v1[(size_t)node * 128 + addr] = acc * 0.17677669529663689f;
}

// ---------------- fused edge MLP + per-node aggregation (1 wave = 1 dst node, no atomics) --------
// R13 = exact R8 kernel (best verified: 203us/dispatch, no scratch pathology). Pad-row skip
// removed — R12 bisection showed the divergent guards trigger ~1.1GB scratch round-trips.
template<int MAT>
__global__ __launch_bounds__(256, 3) void k_edge_agg(
    const float* __restrict__ esc, const int* __restrict__ esrc, const float* __restrict__ eattr,
    const unsigned short* __restrict__ esc_hl, const int* __restrict__ src_s, const float4* __restrict__ y_s,
    const float* __restrict__ s1v1, const int* __restrict__ row_start, const int* __restrict__ eidx,
    const float* __restrict__ w1g, const float* __restrict__ w2g, const float* __restrict__ w3g,
    float* __restrict__ agg)
{
  __shared__ __attribute__((aligned(16))) unsigned short W2T[64 * 72];
  __shared__ __attribute__((aligned(16))) unsigned short W3T[128 * 72];
  __shared__ __attribute__((aligned(16))) unsigned short Hb[4][2][16 * 72];

  const int tid = threadIdx.x, lane = tid & 63, wv = tid >> 6;
  const int c0 = lane & 15, g = lane >> 4;

  for (int idx = tid; idx < 64 * 64; idx += 256) {
    int k = idx >> 6, n2 = idx & 63;
    W2T[n2 * 72 + k] = f2bf(w2g[idx] * 0.125f);      // exact pow2 fold
  }
  for (int idx = tid; idx < 64 * 128; idx += 256) {
    int k = idx >> 7, n2 = idx & 127;
    W3T[n2 * 72 + k] = f2bf(w3g[idx] * 0.125f);      // exact pow2 fold
  }
  // B1 carries 1/sqrt(8): hi/lo split of the scaled weight
  s8v B1[4];
#pragma unroll
  for (int nt = 0; nt < 4; ++nt)
#pragma unroll
    for (int i = 0; i < 8; ++i) {
      float w = w1g[i * 64 + nt * 16 + c0] * 0.35355339059327373f;
      unsigned short hi = f2bf(w);
      B1[nt][i] = (g < 2) ? (short)hi : (short)f2bf(w - bfh2f(hi));
    }
  __syncthreads();   // only block-wide barrier (weight staging)

  unsigned short* hhi = &Hb[wv][0][0];
  unsigned short* hlo = &Hb[wv][1][0];
  const f4v z = {0.f, 0.f, 0.f, 0.f};

  const int node = blockIdx.x * 4 + wv;
  const int jb = row_start[node], je = row_start[node + 1];

  float nacc[16];
#pragma unroll
  for (int k = 0; k < 16; ++k) nacc[k] = 0.f;

  for (int base = jb; base < je; base += 16) {
    const int nvalid = je - base;
    // ---- prefetch per-edge data
    s8v A1 = {0, 0, 0, 0, 0, 0, 0, 0};
    int srcv[4];
    float4 yv[4];
    bool val[4];
    if constexpr (MAT) {
      if (c0 < nvalid)
        A1 = *(const s8v*)(esc_hl + (size_t)(base + c0) * 16 + (size_t)(g & 1) * 8);
#pragma unroll
      for (int i = 0; i < 4; ++i) {
        int s = g * 4 + i;
        val[i] = (s < nvalid);
        srcv[i] = 0; yv[i] = make_float4(0.f, 0.f, 0.f, 0.f);
        if (val[i]) { srcv[i] = src_s[base + s]; yv[i] = y_s[base + s]; }
      }
    } else {
      if (c0 < nvalid) {
        int eid = eidx[base + c0];
        const float4* p = (const float4*)(esc + (size_t)eid * 8);
        float4 a = p[0], b = p[1];
        float e8[8] = {a.x, a.y, a.z, a.w, b.x, b.y, b.z, b.w};
#pragma unroll
        for (int j = 0; j < 8; ++j) {
          unsigned short h, l;
          split_rtz(e8[j], h, l);
          A1[j] = (g & 1) ? (short)l : (short)h;
        }
      }
#pragma unroll
      for (int i = 0; i < 4; ++i) {
        int s = g * 4 + i;
        val[i] = (s < nvalid);
        srcv[i] = 0; yv[i] = make_float4(0.f, 0.f, 0.f, 0.f);
        if (val[i]) {
          int eid = eidx[base + s];
          srcv[i] = esrc[eid];
          yv[i] = *(const float4*)(eattr + (size_t)eid * 4);
        }
      }
    }
    // ---- stage 1: h1 = ssp(es @ W1s)
#pragma unroll
    for (int nt = 0; nt < 4; ++nt) {
      f4v acc = __builtin_amdgcn_mfma_f32_16x16x32_bf16(A1, B1[nt], z, 0, 0, 0);
#pragma unroll
      for (int i = 0; i < 4; ++i) {
        float hv = sspf(acc[i]);
        unsigned short h, l;
        split_rtz(hv, h, l);
        hhi[(g * 4 + i) * 72 + nt * 16 + c0] = h;
        hlo[(g * 4 + i) * 72 + nt * 16 + c0] = l;
      }
    }
    // ---- stage 2: h2 = ssp(h1 @ W2s) (per-wave in-order DS; frags loaded before overwrite)
    s8v A2ah = *(const s8v*)&hhi[c0 * 72 + 8 * g];
    s8v A2bh = *(const s8v*)&hhi[c0 * 72 + 32 + 8 * g];
    s8v A2al = *(const s8v*)&hlo[c0 * 72 + 8 * g];
    s8v A2bl = *(const s8v*)&hlo[c0 * 72 + 32 + 8 * g];
#pragma unroll
    for (int nt = 0; nt < 4; ++nt) {
      s8v Ba = *(const s8v*)&W2T[(nt * 16 + c0) * 72 + 8 * g];
      s8v Bb = *(const s8v*)&W2T[(nt * 16 + c0) * 72 + 32 + 8 * g];
      f4v acc = __builtin_amdgcn_mfma_f32_16x16x32_bf16(A2ah, Ba, z, 0, 0, 0);
      acc = __builtin_amdgcn_mfma_f32_16x16x32_bf16(A2bh, Bb, acc, 0, 0, 0);
      acc = __builtin_amdgcn_mfma_f32_16x16x32_bf16(A2al, Ba, acc, 0, 0, 0);
      acc = __builtin_amdgcn_mfma_f32_16x16x32_bf16(A2bl, Bb, acc, 0, 0, 0);
#pragma unroll
      for (int i = 0; i < 4; ++i) {
        float hv = sspf(acc[i]);
        unsigned short h, l;
        split_rtz(hv, h, l);
        hhi[(g * 4 + i) * 72 + nt * 16 + c0] = h;
        hlo[(g * 4 + i) * 72 + nt * 16 + c0] = l;
      }
    }
    // ---- s1v1 row loads before stage 3 (latency hides under MFMAs)
    float4 pr0[4], pr1[4];
#pragma unroll
    for (int i = 0; i < 4; ++i) {
      if (val[i]) {
        const float* svp = s1v1 + (size_t)srcv[i] * 128 + c0 * 8;
        pr0[i] = *(const float4*)svp;
        pr1[i] = *(const float4*)(svp + 4);
      } else {
        pr0[i] = make_float4(0.f, 0.f, 0.f, 0.f);
        pr1[i] = make_float4(0.f, 0.f, 0.f, 0.f);
      }
    }
    // ---- stage 3: w = h2 @ W3s
    s8v A3ah = *(const s8v*)&hhi[c0 * 72 + 8 * g];
    s8v A3bh = *(const s8v*)&hhi[c0 * 72 + 32 + 8 * g];
    s8v A3al = *(const s8v*)&hlo[c0 * 72 + 8 * g];
    s8v A3bl = *(const s8v*)&hlo[c0 * 72 + 32 + 8 * g];
    f4v acc3[8];
#pragma unroll
    for (int nt = 0; nt < 8; ++nt) {
      s8v Ba = *(const s8v*)&W3T[(nt * 16 + c0) * 72 + 8 * g];
      s8v Bb = *(const s8v*)&W3T[(nt * 16 + c0) * 72 + 32 + 8 * g];
      acc3[nt] = __builtin_amdgcn_mfma_f32_16x16x32_bf16(A3ah, Ba, z, 0, 0, 0);
      acc3[nt] = __builtin_amdgcn_mfma_f32_16x16x32_bf16(A3bh, Bb, acc3[nt], 0, 0, 0);
      acc3[nt] = __builtin_amdgcn_mfma_f32_16x16x32_bf16(A3al, Ba, acc3[nt], 0, 0, 0);
      acc3[nt] = __builtin_amdgcn_mfma_f32_16x16x32_bf16(A3bl, Bb, acc3[nt], 0, 0, 0);
    }
    // ---- epilogue: accumulate per-lane partials (reduce deferred to end of node)
#pragma unroll
    for (int i = 0; i < 4; ++i) {
      if (val[i]) {
        float w0 = acc3[0][i], w1_ = acc3[1][i], w2_ = acc3[2][i], w3_ = acc3[3][i];
        float w4_ = acc3[4][i], w5_ = acc3[5][i], w6_ = acc3[6][i], w7_ = acc3[7][i];
        float4 y = yv[i];
        float sA = pr0[i].x, sB = pr0[i].y;
        float vA0 = pr0[i].z, vA1 = pr0[i].w, vA2 = pr1[i].x;
        float vB0 = pr1[i].y, vB1 = pr1[i].z, vB2 = pr1[i].w;
        nacc[0] += w0 * sA * y.x;
        nacc[1] += w1_ * sB * y.x;
        nacc[2] += w6_ * (vA0 * y.y + vA1 * y.z + vA2 * y.w);
        nacc[3] += w7_ * (vB0 * y.y + vB1 * y.z + vB2 * y.w);
        nacc[4] += w2_ * sA * y.y;  nacc[5] += w2_ * sA * y.z;  nacc[6] += w2_ * sA * y.w;
        nacc[7] += w3_ * sB * y.y;  nacc[8] += w3_ * sB * y.z;  nacc[9] += w3_ * sB * y.w;
        nacc[10] += w4_ * vA0 * y.x; nacc[11] += w4_ * vA1 * y.x; nacc[12] += w4_ * vA2 * y.x;
        nacc[13] += w5_ * vB0 * y.x; nacc[14] += w5_ * vB1 * y.x; nacc[15] += w5_ * vB2 * y.x;
      }
    }
  }
  // ---- one cross-lane reduce per node
#pragma unroll
  for (int k = 0; k < 16; ++k) {
    float v = nacc[k];
    v += __shfl_xor(v, 16, 64);
    v += __shfl_xor(v, 32, 64);
    nacc[k] = v;
  }
  if (g == 0) {
    float* ad = agg + (size_t)node * 256;
    ad[c0] = nacc[0];
    ad[16 + c0] = nacc[1];
    ad[32 + c0] = nacc[2];
    ad[48 + c0] = nacc[3];
#pragma unroll
    for (int c = 0; c < 3; ++c) {
      ad[64 + 3 * c0 + c]  = nacc[4 + c];
      ad[112 + 3 * c0 + c] = nacc[7 + c];
      ad[160 + 3 * c0 + c] = nacc[10 + c];
      ad[208 + 3 * c0 + c] = nacc[13 + c];
    }
  }
}

// ---------------- node_post: lin2 + self-connection + gate + residual ----------------
__global__ __launch_bounds__(256) void k_node_post(
    const float* __restrict__ x, const float* __restrict__ attr, const float* __restrict__ agg,
    const float* __restrict__ l2s, const float* __restrict__ l2v,
    const float* __restrict__ scs, const float* __restrict__ scv,
    float* __restrict__ out)
{
  __shared__ float xa[4][4][136];
  __shared__ float ag[4][4][256];
  const int l = threadIdx.x & 63, wv = threadIdx.x >> 6;
  const int n0 = blockIdx.x * 16 + wv * 4;
#pragma unroll
  for (int b = 0; b < 4; ++b) {
    int nd = n0 + b;
    xa[wv][b][l] = x[(size_t)nd * 128 + l];
    xa[wv][b][64 + l] = x[(size_t)nd * 128 + 64 + l];
    if (l < 8) xa[wv][b][128 + l] = attr[nd * 8 + l];
#pragma unroll
    for (int q = 0; q < 4; ++q) ag[wv][b][q * 64 + l] = agg[(size_t)nd * 256 + q * 64 + l];
  }
  float attr_r[4][8];
#pragma unroll
  for (int b = 0; b < 4; ++b)
#pragma unroll
    for (int a = 0; a < 8; ++a) attr_r[b][a] = xa[wv][b][128 + a];

  const int w1 = l / 3, c1 = l - 3 * w1;
  const int f2 = 64 + l;
  const int w2r = f2 / 3, c2r = f2 - 3 * w2r;
  const int w2 = (l < 32) ? w2r : 0, c2 = (l < 32) ? c2r : 0;

  float acc[4] = {0.f, 0.f, 0.f, 0.f}, sa[4] = {0.f, 0.f, 0.f, 0.f};
  float av1[4] = {0.f, 0.f, 0.f, 0.f}, sv1[4] = {0.f, 0.f, 0.f, 0.f};
  float av2[4] = {0.f, 0.f, 0.f, 0.f}, sv2[4] = {0.f, 0.f, 0.f, 0.f};

#pragma unroll 8
  for (int u = 0; u < 64; ++u) {
    float wl = l2s[u * 64 + l];
#pragma unroll
    for (int b = 0; b < 4; ++b) acc[b] += ag[wv][b][u] * wl;
  }
#pragma unroll 4
  for (int u = 0; u < 64; ++u) {
    float wla = l2v[u * 32 + w1];
    float wlb = l2v[u * 32 + w2];
#pragma unroll
    for (int b = 0; b < 4; ++b) {
      av1[b] += ag[wv][b][64 + 3 * u + c1] * wla;
      av2[b] += ag[wv][b][64 + 3 * u + c2] * wlb;
    }
  }
  for (int u = 0; u < 32; ++u) {
    float sb[4];
#pragma unroll
    for (int b = 0; b < 4; ++b) sb[b] = xa[wv][b][u];
#pragma unroll
    for (int a = 0; a < 8; ++a) {
      float wl = scs[(u * 8 + a) * 64 + l];
#pragma unroll
      for (int b = 0; b < 4; ++b) sa[b] += sb[b] * attr_r[b][a] * wl;
    }
  }
  for (int u = 0; u < 32; ++u) {
    float vb1[4], vb2[4];
#pragma unroll
    for (int b = 0; b < 4; ++b) {
      vb1[b] = xa[wv][b][32 + 3 * u + c1];
      vb2[b] = xa[wv][b][32 + 3 * u + c2];
    }
#pragma unroll
    for (int a = 0; a < 8; ++a) {
      float wla = scv[(u * 8 + a) * 32 + w1];
      float wlb = scv[(u * 8 + a) * 32 + w2];
#pragma unroll
      for (int b = 0; b < 4; ++b) {
        sv1[b] += vb1[b] * attr_r[b][a] * wla;
        sv2[b] += vb2[b] * attr_r[b][a] * wlb;
      }
    }
  }

#pragma unroll
  for (int b = 0; b < 4; ++b) {
    float outs = acc[b] * 0.03125f + sa[b] * 0.0625f;
    float gss = sspf(outs);
    float ov1 = av1[b] * 0.03125f + sv1[b] * 0.0625f;
    float ov2 = av2[b] * 0.03125f + sv2[b] * 0.0625f;
    float gate1 = __shfl(gss, 32 + w1, 64);
    float gate2 = __shfl(gss, 32 + w2, 64);
    float* o = out + (size_t)(n0 + b) * 128;
    if (l < 32) o[l] = xa[wv][b][l] + gss;
    o[32 + l] = xa[wv][b][32 + l] + ov1 * gate1;
    if (l < 32) o[96 + l] = xa[wv][b][96 + l] + ov2 * gate2;
  }
}

extern "C" void kernel_launch(void* const* d_in, const int* in_sizes, int n_in,
                              void* d_out, int out_size, void* d_ws, size_t ws_size,
                              hipStream_t stream) {
  const float* node_input = (const float*)d_in[0];
  const float* node_attr  = (const float*)d_in[1];
  const int*   esrc  = (const int*)d_in[2];
  const int*   edst  = (const int*)d_in[3];
  const float* eattr = (const float*)d_in[4];
  const float* escal = (const float*)d_in[5];
  const float* l1s = (const float*)d_in[6];
  const float* l1v = (const float*)d_in[7];
  const float* w1  = (const float*)d_in[8];
  const float* w2  = (const float*)d_in[9];
  const float* w3  = (const float*)d_in[10];
  const float* l2s = (const float*)d_in[11];
  const float* l2v = (const float*)d_in[12];
  const float* scs = (const float*)d_in[13];
  const float* scv = (const float*)d_in[14];
  float* out  = (float*)d_out;

  char* p = (char*)d_ws;
  float* s1v1 = (float*)p;                 p += (size_t)N_NODES * 128 * 4;
  float* agg  = (float*)p;                 p += (size_t)N_NODES * 256 * 4;
  int* eidx   = (int*)p;                   p += (size_t)N_EDGES * 4;
  unsigned short* esc_hl = (unsigned short*)p;  p += (size_t)N_EDGES * 16 * 2;
  float4* y_s = (float4*)p;                p += (size_t)N_EDGES * 16;
  int* src_s  = (int*)p;                   p += (size_t)N_EDGES * 4;
  size_t need_mat = (size_t)(p - (char*)d_ws) + (size_t)(N_NODES * 2 + 1) * 4;
  char* tail = ((size_t)ws_size >= need_mat) ? p : (char*)(eidx + N_EDGES);
  int* counts    = (int*)tail;
  int* row_start = counts + N_NODES;
  int* cursor    = row_start + N_NODES + 1;
  const bool use_mat = ((size_t)ws_size >= need_mat);

  (void)hipMemsetAsync(counts, 0, (size_t)N_NODES * sizeof(int), stream);
  k_hist<<<(N_EDGES + 255) / 256, 256, 0, stream>>>(edst, counts);
  k_scan<<<1, SCAN_T, 0, stream>>>(counts, row_start, cursor);
  k_scatter<<<(N_EDGES + 255) / 256, 256, 0, stream>>>(edst, cursor, eidx);
  if (use_mat)
    k_sortmat<<<(N_NODES * 64 + 255) / 256, 256, 0, stream>>>(row_start, eidx,
        esrc, escal, eattr, esc_hl, y_s, src_s);
  else
    k_sortseg<<<(N_NODES * 64 + 255) / 256, 256, 0, stream>>>(row_start, eidx);

  for (int layer = 0; layer < 3; ++layer) {
    const float* xin = (layer == 0) ? node_input : (const float*)out;
    k_node_pre<<<N_NODES * 128 / 256, 256, 0, stream>>>(
        xin, l1s + layer * 1024, l1v + layer * 1024, s1v1);
    if (use_mat)
      k_edge_agg<1><<<N_NODES / 4, 256, 0, stream>>>(escal, esrc, eattr, esc_hl, src_s, y_s,
          s1v1, row_start, eidx, w1 + layer * 512, w2 + layer * 4096, w3 + layer * 8192, agg);
    else
      k_edge_agg<0><<<N_NODES / 4, 256, 0, stream>>>(escal, esrc, eattr, esc_hl, src_s, y_s,
          s1v1, row_start, eidx, w1 + layer * 512, w2 + layer * 4096, w3 + layer * 8192, agg);
    k_node_post<<<N_NODES / 16, 256, 0, stream>>>(xin, node_attr, agg,
        l2s + layer * 4096, l2v + layer * 2048, scs + layer * 16384, scv + layer * 8192, out);
  }
}

// Round 15
// 1191.705 us; speedup vs baseline: 1.9317x; 1.0002x over previous
//
#include <hip/hip_runtime.h>
#include <math.h>

#define N_NODES 30000
#define N_EDGES 480000

typedef __attribute__((ext_vector_type(8))) short s8v;   // 8 x bf16 (as i16 bits)
typedef __attribute__((ext_vector_type(4))) float f4v;

__device__ inline unsigned short f2bf(float f) {  // RNE (weights, staged once)
  union { float f; unsigned u; } v; v.f = f;
  return (unsigned short)((v.u + 0x7fffu + ((v.u >> 16) & 1u)) >> 16);
}
__device__ inline float bfh2f(unsigned short h) {
  union { unsigned u; float f; } v; v.u = (unsigned)h << 16; return v.f;
}
// cheap RTZ hi/lo split: hi+lo captures 16 mantissa bits (err ~2^-16 rel), 4 VALU ops
__device__ inline void split_rtz(float x, unsigned short& hi, unsigned short& lo) {
  unsigned u = __float_as_uint(x);
  hi = (unsigned short)(u >> 16);
  float hf = __uint_as_float(u & 0xffff0000u);
  lo = (unsigned short)(__float_as_uint(x - hf) >> 16);
}
// fast softplus(x) - log2: native exp/log (v_exp_f32/v_log_f32), no branches
__device__ inline float sspf(float x) {
  float t = __expf(-fabsf(x));
  return fmaxf(x, 0.f) + __logf(1.f + t) - 0.69314718055994531f;
}

// ---------------- CSR build (once per launch; edge_dst identical across layers) ----------------
__global__ __launch_bounds__(256) void k_hist(const int* __restrict__ edst, int* __restrict__ counts) {
  int e = blockIdx.x * 256 + threadIdx.x;
  if (e < N_EDGES) atomicAdd(&counts[edst[e]], 1);
}

#define SCAN_T 1024
#define NPER 30
__global__ __launch_bounds__(1024) void k_scan(const int* __restrict__ counts,
                                               int* __restrict__ row_start, int* __restrict__ cursor) {
  __shared__ int part[SCAN_T];
  int t = threadIdx.x;
  int base = t * NPER;
  int local[NPER];
  int s = 0;
#pragma unroll
  for (int j = 0; j < NPER; ++j) {
    int idx = base + j;
    int c = (idx < N_NODES) ? counts[idx] : 0;
    local[j] = s;
    s += c;
  }
  part[t] = s;
  __syncthreads();
  for (int off = 1; off < SCAN_T; off <<= 1) {
    int v = (t >= off) ? part[t - off] : 0;
    __syncthreads();
    part[t] += v;
    __syncthreads();
  }
  int pre = (t == 0) ? 0 : part[t - 1];
#pragma unroll
  for (int j = 0; j < NPER; ++j) {
    int idx = base + j;
    if (idx < N_NODES) {
      int v = pre + local[j];
      row_start[idx] = v;
      cursor[idx] = v;
    }
  }
  if (t == SCAN_T - 1) row_start[N_NODES] = pre + s;
}

__global__ __launch_bounds__(256) void k_scatter(const int* __restrict__ edst,
                                                 int* __restrict__ cursor, int* __restrict__ eidx) {
  int e = blockIdx.x * 256 + threadIdx.x;
  if (e < N_EDGES) {
    int pos = atomicAdd(&cursor[edst[e]], 1);
    eidx[pos] = e;
  }
}

// fallback (no-MAT): sort each segment for determinism
__global__ __launch_bounds__(256) void k_sortseg(const int* __restrict__ row_start, int* __restrict__ eidx) {
  int wid = (blockIdx.x * 256 + threadIdx.x) >> 6;
  int lane = threadIdx.x & 63;
  if (wid >= N_NODES) return;
  int jb = row_start[wid], je = row_start[wid + 1];
  int deg = je - jb;
  if (deg <= 1) return;
  if (deg <= 64) {
    int key = (lane < deg) ? eidx[jb + lane] : 0x7fffffff;
#pragma unroll
    for (int k = 2; k <= 64; k <<= 1)
      for (int j = k >> 1; j > 0; j >>= 1) {
        int other = __shfl_xor(key, j, 64);
        bool asc = ((lane & k) == 0);
        bool upper = ((lane & j) != 0);
        key = (upper == asc) ? max(key, other) : min(key, other);
      }
    if (lane < deg) eidx[jb + lane] = key;
  } else if (lane == 0) {
    for (int i = jb + 1; i < je; ++i) {
      int v = eidx[i];
      int j = i - 1;
      while (j >= jb && eidx[j] > v) { eidx[j + 1] = eidx[j]; --j; }
      eidx[j + 1] = v;
    }
  }
}

// ---------------- fused sort + materialize (1 wave = 1 dst node, once per launch) ------------
// sorts segment keys in-register (deterministic), then emits sorted per-edge data directly:
// esc_hl[pos]: [8 bf16-hi | 8 bf16-lo]; y_s[pos]=eattr; src_s[pos]=esrc.
__global__ __launch_bounds__(256) void k_sortmat(const int* __restrict__ row_start, int* __restrict__ eidx,
    const int* __restrict__ esrc, const float* __restrict__ esc, const float* __restrict__ eattr,
    unsigned short* __restrict__ esc_hl, float4* __restrict__ y_s, int* __restrict__ src_s) {
  int wid = (blockIdx.x * 256 + threadIdx.x) >> 6;
  int lane = threadIdx.x & 63;
  if (wid >= N_NODES) return;
  int jb = row_start[wid], je = row_start[wid + 1];
  int deg = je - jb;
  if (deg <= 0) return;
  if (deg <= 64) {
    int key = (lane < deg) ? eidx[jb + lane] : 0x7fffffff;
#pragma unroll
    for (int k = 2; k <= 64; k <<= 1)
      for (int j = k >> 1; j > 0; j >>= 1) {
        int other = __shfl_xor(key, j, 64);
        bool asc = ((lane & k) == 0);
        bool upper = ((lane & j) != 0);
        key = (upper == asc) ? max(key, other) : min(key, other);
      }
    if (lane < deg) {
      int p = jb + lane, e = key;
      src_s[p] = esrc[e];
      y_s[p] = *(const float4*)(eattr + (size_t)e * 4);
      const float4* q = (const float4*)(esc + (size_t)e * 8);
      float4 a = q[0], b = q[1];
      float e8[8] = {a.x, a.y, a.z, a.w, b.x, b.y, b.z, b.w};
      s8v hi, lo;
#pragma unroll
      for (int j = 0; j < 8; ++j) {
        unsigned short h, l;
        split_rtz(e8[j], h, l);
        hi[j] = (short)h; lo[j] = (short)l;
      }
      *(s8v*)(esc_hl + (size_t)p * 16) = hi;
      *(s8v*)(esc_hl + (size_t)p * 16 + 8) = lo;
    }
  } else {
    if (lane == 0) {  // rare fallback
      for (int i = jb + 1; i < je; ++i) {
        int v = eidx[i];
        int j = i - 1;
        while (j >= jb && eidx[j] > v) { eidx[j + 1] = eidx[j]; --j; }
        eidx[j + 1] = v;
      }
    }
    for (int p = jb + lane; p < je; p += 64) {
      int e = eidx[p];
      src_s[p] = esrc[e];
      y_s[p] = *(const float4*)(eattr + (size_t)e * 4);
      const float4* q = (const float4*)(esc + (size_t)e * 8);
      float4 a = q[0], b = q[1];
      float e8[8] = {a.x, a.y, a.z, a.w, b.x, b.y, b.z, b.w};
      s8v hi, lo;
#pragma unroll
      for (int j = 0; j < 8; ++j) {
        unsigned short h, l;
        split_rtz(e8[j], h, l);
        hi[j] = (short)h; lo[j] = (short)l;
      }
      *(s8v*)(esc_hl + (size_t)p * 16) = hi;
      *(s8v*)(esc_hl + (size_t)p * 16 + 8) = lo;
    }
  }
}

// ---------------- node_pre: low-divergence compute, permuted store into interleaved layout -------
// s1v1 row: slot(0..15)*8 + {0:s1[slot],1:s1[slot+16],2+c:v1[slot][c],5+c:v1[slot+16][c]}
__global__ __launch_bounds__(256) void k_node_pre(const float* __restrict__ x,
    const float* __restrict__ l1s, const float* __restrict__ l1v,
    float* __restrict__ s1v1)
{
  int t = blockIdx.x * 256 + threadIdx.x;
  int node = t >> 7, j = t & 127;
  const float* xr = x + (size_t)node * 128;
  float acc = 0.f;
  int addr;
  if (j < 32) {
    int m = j;
#pragma unroll
    for (int u = 0; u < 32; ++u) acc += xr[u] * l1s[u * 32 + m];
    addr = (m & 15) * 8 + (m >> 4);
  } else {
    int jj = j - 32, m = jj / 3, c = jj - 3 * m;
#pragma unroll
    for (int u = 0; u < 32; ++u) acc += xr[32 + u * 3 + c] * l1v[u * 32 + m];
    addr = (m & 15) * 8 + 2 + (m >> 4) * 3 + c;
  }
  s1v1[(size_t)node * 128 + addr] = acc * 0.17677669529663689f;
}

// ---------------- fused edge MLP + per-node aggregation (1 wave = 1 dst node, no atomics) --------
// Verified-best configuration (r8/r13): stride-72 padded LDS, per-tile B LDS reads, (256,3),
// unconditional h writes (pad rows compute garbage that is never consumed — guards cause spills).
template<int MAT>
__global__ __launch_bounds__(256, 3) void k_edge_agg(
    const float* __restrict__ esc, const int* __restrict__ esrc, const float* __restrict__ eattr,
    const unsigned short* __restrict__ esc_hl, const int* __restrict__ src_s, const float4* __restrict__ y_s,
    const float* __restrict__ s1v1, const int* __restrict__ row_start, const int* __restrict__ eidx,
    const float* __restrict__ w1g, const float* __restrict__ w2g, const float* __restrict__ w3g,
    float* __restrict__ agg)
{
  __shared__ __attribute__((aligned(16))) unsigned short W2T[64 * 72];
  __shared__ __attribute__((aligned(16))) unsigned short W3T[128 * 72];
  __shared__ __attribute__((aligned(16))) unsigned short Hb[4][2][16 * 72];

  const int tid = threadIdx.x, lane = tid & 63, wv = tid >> 6;
  const int c0 = lane & 15, g = lane >> 4;

  for (int idx = tid; idx < 64 * 64; idx += 256) {
    int k = idx >> 6, n2 = idx & 63;
    W2T[n2 * 72 + k] = f2bf(w2g[idx] * 0.125f);      // exact pow2 fold
  }
  for (int idx = tid; idx < 64 * 128; idx += 256) {
    int k = idx >> 7, n2 = idx & 127;
    W3T[n2 * 72 + k] = f2bf(w3g[idx] * 0.125f);      // exact pow2 fold
  }
  // B1 carries 1/sqrt(8): hi/lo split of the scaled weight
  s8v B1[4];
#pragma unroll
  for (int nt = 0; nt < 4; ++nt)
#pragma unroll
    for (int i = 0; i < 8; ++i) {
      float w = w1g[i * 64 + nt * 16 + c0] * 0.35355339059327373f;
      unsigned short hi = f2bf(w);
      B1[nt][i] = (g < 2) ? (short)hi : (short)f2bf(w - bfh2f(hi));
    }
  __syncthreads();   // only block-wide barrier (weight staging)

  unsigned short* hhi = &Hb[wv][0][0];
  unsigned short* hlo = &Hb[wv][1][0];
  const f4v z = {0.f, 0.f, 0.f, 0.f};

  const int node = blockIdx.x * 4 + wv;
  const int jb = row_start[node], je = row_start[node + 1];

  float nacc[16];
#pragma unroll
  for (int k = 0; k < 16; ++k) nacc[k] = 0.f;

  for (int base = jb; base < je; base += 16) {
    const int nvalid = je - base;
    // ---- prefetch per-edge data
    s8v A1 = {0, 0, 0, 0, 0, 0, 0, 0};
    int srcv[4];
    float4 yv[4];
    bool val[4];
    if constexpr (MAT) {
      if (c0 < nvalid)
        A1 = *(const s8v*)(esc_hl + (size_t)(base + c0) * 16 + (size_t)(g & 1) * 8);
#pragma unroll
      for (int i = 0; i < 4; ++i) {
        int s = g * 4 + i;
        val[i] = (s < nvalid);
        srcv[i] = 0; yv[i] = make_float4(0.f, 0.f, 0.f, 0.f);
        if (val[i]) { srcv[i] = src_s[base + s]; yv[i] = y_s[base + s]; }
      }
    } else {
      if (c0 < nvalid) {
        int eid = eidx[base + c0];
        const float4* p = (const float4*)(esc + (size_t)eid * 8);
        float4 a = p[0], b = p[1];
        float e8[8] = {a.x, a.y, a.z, a.w, b.x, b.y, b.z, b.w};
#pragma unroll
        for (int j = 0; j < 8; ++j) {
          unsigned short h, l;
          split_rtz(e8[j], h, l);
          A1[j] = (g & 1) ? (short)l : (short)h;
        }
      }
#pragma unroll
      for (int i = 0; i < 4; ++i) {
        int s = g * 4 + i;
        val[i] = (s < nvalid);
        srcv[i] = 0; yv[i] = make_float4(0.f, 0.f, 0.f, 0.f);
        if (val[i]) {
          int eid = eidx[base + s];
          srcv[i] = esrc[eid];
          yv[i] = *(const float4*)(eattr + (size_t)eid * 4);
        }
      }
    }
    // ---- stage 1: h1 = ssp(es @ W1s)
#pragma unroll
    for (int nt = 0; nt < 4; ++nt) {
      f4v acc = __builtin_amdgcn_mfma_f32_16x16x32_bf16(A1, B1[nt], z, 0, 0, 0);
#pragma unroll
      for (int i = 0; i < 4; ++i) {
        float hv = sspf(acc[i]);
        unsigned short h, l;
        split_rtz(hv, h, l);
        hhi[(g * 4 + i) * 72 + nt * 16 + c0] = h;
        hlo[(g * 4 + i) * 72 + nt * 16 + c0] = l;
      }
    }
    // ---- stage 2: h2 = ssp(h1 @ W2s) (per-wave in-order DS; frags loaded before overwrite)
    s8v A2ah = *(const s8v*)&hhi[c0 * 72 + 8 * g];
    s8v A2bh = *(const s8v*)&hhi[c0 * 72 + 32 + 8 * g];
    s8v A2al = *(const s8v*)&hlo[c0 * 72 + 8 * g];
    s8v A2bl = *(const s8v*)&hlo[c0 * 72 + 32 + 8 * g];
#pragma unroll
    for (int nt = 0; nt < 4; ++nt) {
      s8v Ba = *(const s8v*)&W2T[(nt * 16 + c0) * 72 + 8 * g];
      s8v Bb = *(const s8v*)&W2T[(nt * 16 + c0) * 72 + 32 + 8 * g];
      f4v acc = __builtin_amdgcn_mfma_f32_16x16x32_bf16(A2ah, Ba, z, 0, 0, 0);
      acc = __builtin_amdgcn_mfma_f32_16x16x32_bf16(A2bh, Bb, acc, 0, 0, 0);
      acc = __builtin_amdgcn_mfma_f32_16x16x32_bf16(A2al, Ba, acc, 0, 0, 0);
      acc = __builtin_amdgcn_mfma_f32_16x16x32_bf16(A2bl, Bb, acc, 0, 0, 0);
#pragma unroll
      for (int i = 0; i < 4; ++i) {
        float hv = sspf(acc[i]);
        unsigned short h, l;
        split_rtz(hv, h, l);
        hhi[(g * 4 + i) * 72 + nt * 16 + c0] = h;
        hlo[(g * 4 + i) * 72 + nt * 16 + c0] = l;
      }
    }
    // ---- s1v1 row loads before stage 3 (latency hides under MFMAs)
    float4 pr0[4], pr1[4];
#pragma unroll
    for (int i = 0; i < 4; ++i) {
      if (val[i]) {
        const float* svp = s1v1 + (size_t)srcv[i] * 128 + c0 * 8;
        pr0[i] = *(const float4*)svp;
        pr1[i] = *(const float4*)(svp + 4);
      } else {
        pr0[i] = make_float4(0.f, 0.f, 0.f, 0.f);
        pr1[i] = make_float4(0.f, 0.f, 0.f, 0.f);
      }
    }
    // ---- stage 3: w = h2 @ W3s
    s8v A3ah = *(const s8v*)&hhi[c0 * 72 + 8 * g];
    s8v A3bh = *(const s8v*)&hhi[c0 * 72 + 32 + 8 * g];
    s8v A3al = *(const s8v*)&hlo[c0 * 72 + 8 * g];
    s8v A3bl = *(const s8v*)&hlo[c0 * 72 + 32 + 8 * g];
    f4v acc3[8];
#pragma unroll
    for (int nt = 0; nt < 8; ++nt) {
      s8v Ba = *(const s8v*)&W3T[(nt * 16 + c0) * 72 + 8 * g];
      s8v Bb = *(const s8v*)&W3T[(nt * 16 + c0) * 72 + 32 + 8 * g];
      acc3[nt] = __builtin_amdgcn_mfma_f32_16x16x32_bf16(A3ah, Ba, z, 0, 0, 0);
      acc3[nt] = __builtin_amdgcn_mfma_f32_16x16x32_bf16(A3bh, Bb, acc3[nt], 0, 0, 0);
      acc3[nt] = __builtin_amdgcn_mfma_f32_16x16x32_bf16(A3al, Ba, acc3[nt], 0, 0, 0);
      acc3[nt] = __builtin_amdgcn_mfma_f32_16x16x32_bf16(A3bl, Bb, acc3[nt], 0, 0, 0);
    }
    // ---- epilogue: accumulate per-lane partials (reduce deferred to end of node)
#pragma unroll
    for (int i = 0; i < 4; ++i) {
      if (val[i]) {
        float w0 = acc3[0][i], w1_ = acc3[1][i], w2_ = acc3[2][i], w3_ = acc3[3][i];
        float w4_ = acc3[4][i], w5_ = acc3[5][i], w6_ = acc3[6][i], w7_ = acc3[7][i];
        float4 y = yv[i];
        float sA = pr0[i].x, sB = pr0[i].y;
        float vA0 = pr0[i].z, vA1 = pr0[i].w, vA2 = pr1[i].x;
        float vB0 = pr1[i].y, vB1 = pr1[i].z, vB2 = pr1[i].w;
        nacc[0] += w0 * sA * y.x;
        nacc[1] += w1_ * sB * y.x;
        nacc[2] += w6_ * (vA0 * y.y + vA1 * y.z + vA2 * y.w);
        nacc[3] += w7_ * (vB0 * y.y + vB1 * y.z + vB2 * y.w);
        nacc[4] += w2_ * sA * y.y;  nacc[5] += w2_ * sA * y.z;  nacc[6] += w2_ * sA * y.w;
        nacc[7] += w3_ * sB * y.y;  nacc[8] += w3_ * sB * y.z;  nacc[9] += w3_ * sB * y.w;
        nacc[10] += w4_ * vA0 * y.x; nacc[11] += w4_ * vA1 * y.x; nacc[12] += w4_ * vA2 * y.x;
        nacc[13] += w5_ * vB0 * y.x; nacc[14] += w5_ * vB1 * y.x; nacc[15] += w5_ * vB2 * y.x;
      }
    }
  }
  // ---- one cross-lane reduce per node
#pragma unroll
  for (int k = 0; k < 16; ++k) {
    float v = nacc[k];
    v += __shfl_xor(v, 16, 64);
    v += __shfl_xor(v, 32, 64);
    nacc[k] = v;
  }
  if (g == 0) {
    float* ad = agg + (size_t)node * 256;
    ad[c0] = nacc[0];
    ad[16 + c0] = nacc[1];
    ad[32 + c0] = nacc[2];
    ad[48 + c0] = nacc[3];
#pragma unroll
    for (int c = 0; c < 3; ++c) {
      ad[64 + 3 * c0 + c]  = nacc[4 + c];
      ad[112 + 3 * c0 + c] = nacc[7 + c];
      ad[160 + 3 * c0 + c] = nacc[10 + c];
      ad[208 + 3 * c0 + c] = nacc[13 + c];
    }
  }
}

// ---------------- node_post: lin2 + self-connection + gate + residual ----------------
__global__ __launch_bounds__(256) void k_node_post(
    const float* __restrict__ x, const float* __restrict__ attr, const float* __restrict__ agg,
    const float* __restrict__ l2s, const float* __restrict__ l2v,
    const float* __restrict__ scs, const float* __restrict__ scv,
    float* __restrict__ out)
{
  __shared__ float xa[4][4][136];
  __shared__ float ag[4][4][256];
  const int l = threadIdx.x & 63, wv = threadIdx.x >> 6;
  const int n0 = blockIdx.x * 16 + wv * 4;
#pragma unroll
  for (int b = 0; b < 4; ++b) {
    int nd = n0 + b;
    xa[wv][b][l] = x[(size_t)nd * 128 + l];
    xa[wv][b][64 + l] = x[(size_t)nd * 128 + 64 + l];
    if (l < 8) xa[wv][b][128 + l] = attr[nd * 8 + l];
#pragma unroll
    for (int q = 0; q < 4; ++q) ag[wv][b][q * 64 + l] = agg[(size_t)nd * 256 + q * 64 + l];
  }
  float attr_r[4][8];
#pragma unroll
  for (int b = 0; b < 4; ++b)
#pragma unroll
    for (int a = 0; a < 8; ++a) attr_r[b][a] = xa[wv][b][128 + a];

  const int w1 = l / 3, c1 = l - 3 * w1;
  const int f2 = 64 + l;
  const int w2r = f2 / 3, c2r = f2 - 3 * w2r;
  const int w2 = (l < 32) ? w2r : 0, c2 = (l < 32) ? c2r : 0;

  float acc[4] = {0.f, 0.f, 0.f, 0.f}, sa[4] = {0.f, 0.f, 0.f, 0.f};
  float av1[4] = {0.f, 0.f, 0.f, 0.f}, sv1[4] = {0.f, 0.f, 0.f, 0.f};
  float av2[4] = {0.f, 0.f, 0.f, 0.f}, sv2[4] = {0.f, 0.f, 0.f, 0.f};

#pragma unroll 8
  for (int u = 0; u < 64; ++u) {
    float wl = l2s[u * 64 + l];
#pragma unroll
    for (int b = 0; b < 4; ++b) acc[b] += ag[wv][b][u] * wl;
  }
#pragma unroll 4
  for (int u = 0; u < 64; ++u) {
    float wla = l2v[u * 32 + w1];
    float wlb = l2v[u * 32 + w2];
#pragma unroll
    for (int b = 0; b < 4; ++b) {
      av1[b] += ag[wv][b][64 + 3 * u + c1] * wla;
      av2[b] += ag[wv][b][64 + 3 * u + c2] * wlb;
    }
  }
  for (int u = 0; u < 32; ++u) {
    float sb[4];
#pragma unroll
    for (int b = 0; b < 4; ++b) sb[b] = xa[wv][b][u];
#pragma unroll
    for (int a = 0; a < 8; ++a) {
      float wl = scs[(u * 8 + a) * 64 + l];
#pragma unroll
      for (int b = 0; b < 4; ++b) sa[b] += sb[b] * attr_r[b][a] * wl;
    }
  }
  for (int u = 0; u < 32; ++u) {
    float vb1[4], vb2[4];
#pragma unroll
    for (int b = 0; b < 4; ++b) {
      vb1[b] = xa[wv][b][32 + 3 * u + c1];
      vb2[b] = xa[wv][b][32 + 3 * u + c2];
    }
#pragma unroll
    for (int a = 0; a < 8; ++a) {
      float wla = scv[(u * 8 + a) * 32 + w1];
      float wlb = scv[(u * 8 + a) * 32 + w2];
#pragma unroll
      for (int b = 0; b < 4; ++b) {
        sv1[b] += vb1[b] * attr_r[b][a] * wla;
        sv2[b] += vb2[b] * attr_r[b][a] * wlb;
      }
    }
  }

#pragma unroll
  for (int b = 0; b < 4; ++b) {
    float outs = acc[b] * 0.03125f + sa[b] * 0.0625f;
    float gss = sspf(outs);
    float ov1 = av1[b] * 0.03125f + sv1[b] * 0.0625f;
    float ov2 = av2[b] * 0.03125f + sv2[b] * 0.0625f;
    float gate1 = __shfl(gss, 32 + w1, 64);
    float gate2 = __shfl(gss, 32 + w2, 64);
    float* o = out + (size_t)(n0 + b) * 128;
    if (l < 32) o[l] = xa[wv][b][l] + gss;
    o[32 + l] = xa[wv][b][32 + l] + ov1 * gate1;
    if (l < 32) o[96 + l] = xa[wv][b][96 + l] + ov2 * gate2;
  }
}

extern "C" void kernel_launch(void* const* d_in, const int* in_sizes, int n_in,
                              void* d_out, int out_size, void* d_ws, size_t ws_size,
                              hipStream_t stream) {
  const float* node_input = (const float*)d_in[0];
  const float* node_attr  = (const float*)d_in[1];
  const int*   esrc  = (const int*)d_in[2];
  const int*   edst  = (const int*)d_in[3];
  const float* eattr = (const float*)d_in[4];
  const float* escal = (const float*)d_in[5];
  const float* l1s = (const float*)d_in[6];
  const float* l1v = (const float*)d_in[7];
  const float* w1  = (const float*)d_in[8];
  const float* w2  = (const float*)d_in[9];
  const float* w3  = (const float*)d_in[10];
  const float* l2s = (const float*)d_in[11];
  const float* l2v = (const float*)d_in[12];
  const float* scs = (const float*)d_in[13];
  const float* scv = (const float*)d_in[14];
  float* out  = (float*)d_out;

  char* p = (char*)d_ws;
  float* s1v1 = (float*)p;                 p += (size_t)N_NODES * 128 * 4;
  float* agg  = (float*)p;                 p += (size_t)N_NODES * 256 * 4;
  int* eidx   = (int*)p;                   p += (size_t)N_EDGES * 4;
  unsigned short* esc_hl = (unsigned short*)p;  p += (size_t)N_EDGES * 16 * 2;
  float4* y_s = (float4*)p;                p += (size_t)N_EDGES * 16;
  int* src_s  = (int*)p;                   p += (size_t)N_EDGES * 4;
  size_t need_mat = (size_t)(p - (char*)d_ws) + (size_t)(N_NODES * 2 + 1) * 4;
  char* tail = ((size_t)ws_size >= need_mat) ? p : (char*)(eidx + N_EDGES);
  int* counts    = (int*)tail;
  int* row_start = counts + N_NODES;
  int* cursor    = row_start + N_NODES + 1;
  const bool use_mat = ((size_t)ws_size >= need_mat);

  (void)hipMemsetAsync(counts, 0, (size_t)N_NODES * sizeof(int), stream);
  k_hist<<<(N_EDGES + 255) / 256, 256, 0, stream>>>(edst, counts);
  k_scan<<<1, SCAN_T, 0, stream>>>(counts, row_start, cursor);
  k_scatter<<<(N_EDGES + 255) / 256, 256, 0, stream>>>(edst, cursor, eidx);
  if (use_mat)
    k_sortmat<<<(N_NODES * 64 + 255) / 256, 256, 0, stream>>>(row_start, eidx,
        esrc, escal, eattr, esc_hl, y_s, src_s);
  else
    k_sortseg<<<(N_NODES * 64 + 255) / 256, 256, 0, stream>>>(row_start, eidx);

  for (int layer = 0; layer < 3; ++layer) {
    const float* xin = (layer == 0) ? node_input : (const float*)out;
    k_node_pre<<<N_NODES * 128 / 256, 256, 0, stream>>>(
        xin, l1s + layer * 1024, l1v + layer * 1024, s1v1);
    if (use_mat)
      k_edge_agg<1><<<N_NODES / 4, 256, 0, stream>>>(escal, esrc, eattr, esc_hl, src_s, y_s,
          s1v1, row_start, eidx, w1 + layer * 512, w2 + layer * 4096, w3 + layer * 8192, agg);
    else
      k_edge_agg<0><<<N_NODES / 4, 256, 0, stream>>>(escal, esrc, eattr, esc_hl, src_s, y_s,
          s1v1, row_start, eidx, w1 + layer * 512, w2 + layer * 4096, w3 + layer * 8192, agg);
    k_node_post<<<N_NODES / 16, 256, 0, stream>>>(xin, node_attr, agg,
        l2s + layer * 4096, l2v + layer * 2048, scs + layer * 16384, scv + layer * 8192, out);
  }
}

// Round 16
// 1191.444 us; speedup vs baseline: 1.9321x; 1.0002x over previous
//
#include <hip/hip_runtime.h>
#include <math.h>

#define N_NODES 30000
#define N_EDGES 480000

typedef __attribute__((ext_vector_type(8))) short s8v;   // 8 x bf16 (as i16 bits)
typedef __attribute__((ext_vector_type(4))) float f4v;

__device__ inline unsigned short f2bf(float f) {  // RNE (weights, staged once)
  union { float f; unsigned u; } v; v.f = f;
  return (unsigned short)((v.u + 0x7fffu + ((v.u >> 16) & 1u)) >> 16);
}
__device__ inline float bfh2f(unsigned short h) {
  union { unsigned u; float f; } v; v.u = (unsigned)h << 16; return v.f;
}
// cheap RTZ hi/lo split: hi+lo captures 16 mantissa bits (err ~2^-16 rel), 4 VALU ops
__device__ inline void split_rtz(float x, unsigned short& hi, unsigned short& lo) {
  unsigned u = __float_as_uint(x);
  hi = (unsigned short)(u >> 16);
  float hf = __uint_as_float(u & 0xffff0000u);
  lo = (unsigned short)(__float_as_uint(x - hf) >> 16);
}
// fast softplus(x) - log2: native exp/log (v_exp_f32/v_log_f32), no branches
__device__ inline float sspf(float x) {
  float t = __expf(-fabsf(x));
  return fmaxf(x, 0.f) + __logf(1.f + t) - 0.69314718055994531f;
}

// ---------------- CSR build (once per launch; edge_dst identical across layers) ----------------
__global__ __launch_bounds__(256) void k_hist(const int* __restrict__ edst, int* __restrict__ counts) {
  int e = blockIdx.x * 256 + threadIdx.x;
  if (e < N_EDGES) atomicAdd(&counts[edst[e]], 1);
}

#define SCAN_T 1024
#define NPER 30
__global__ __launch_bounds__(1024) void k_scan(const int* __restrict__ counts,
                                               int* __restrict__ row_start, int* __restrict__ cursor) {
  __shared__ int part[SCAN_T];
  int t = threadIdx.x;
  int base = t * NPER;
  int local[NPER];
  int s = 0;
#pragma unroll
  for (int j = 0; j < NPER; ++j) {
    int idx = base + j;
    int c = (idx < N_NODES) ? counts[idx] : 0;
    local[j] = s;
    s += c;
  }
  part[t] = s;
  __syncthreads();
  for (int off = 1; off < SCAN_T; off <<= 1) {
    int v = (t >= off) ? part[t - off] : 0;
    __syncthreads();
    part[t] += v;
    __syncthreads();
  }
  int pre = (t == 0) ? 0 : part[t - 1];
#pragma unroll
  for (int j = 0; j < NPER; ++j) {
    int idx = base + j;
    if (idx < N_NODES) {
      int v = pre + local[j];
      row_start[idx] = v;
      cursor[idx] = v;
    }
  }
  if (t == SCAN_T - 1) row_start[N_NODES] = pre + s;
}

__global__ __launch_bounds__(256) void k_scatter(const int* __restrict__ edst,
                                                 int* __restrict__ cursor, int* __restrict__ eidx) {
  int e = blockIdx.x * 256 + threadIdx.x;
  if (e < N_EDGES) {
    int pos = atomicAdd(&cursor[edst[e]], 1);
    eidx[pos] = e;
  }
}

// fallback (no-MAT): sort each segment for determinism
__global__ __launch_bounds__(256) void k_sortseg(const int* __restrict__ row_start, int* __restrict__ eidx) {
  int wid = (blockIdx.x * 256 + threadIdx.x) >> 6;
  int lane = threadIdx.x & 63;
  if (wid >= N_NODES) return;
  int jb = row_start[wid], je = row_start[wid + 1];
  int deg = je - jb;
  if (deg <= 1) return;
  if (deg <= 64) {
    int key = (lane < deg) ? eidx[jb + lane] : 0x7fffffff;
#pragma unroll
    for (int k = 2; k <= 64; k <<= 1)
      for (int j = k >> 1; j > 0; j >>= 1) {
        int other = __shfl_xor(key, j, 64);
        bool asc = ((lane & k) == 0);
        bool upper = ((lane & j) != 0);
        key = (upper == asc) ? max(key, other) : min(key, other);
      }
    if (lane < deg) eidx[jb + lane] = key;
  } else if (lane == 0) {
    for (int i = jb + 1; i < je; ++i) {
      int v = eidx[i];
      int j = i - 1;
      while (j >= jb && eidx[j] > v) { eidx[j + 1] = eidx[j]; --j; }
      eidx[j + 1] = v;
    }
  }
}

// ---------------- fused sort + materialize (1 wave = 1 dst node, once per launch) ------------
// sorts segment keys in-register (deterministic), then emits sorted per-edge data directly:
// esc_hl[pos]: [8 bf16-hi | 8 bf16-lo]; y_s[pos]=eattr; src_s[pos]=esrc.
__global__ __launch_bounds__(256) void k_sortmat(const int* __restrict__ row_start, int* __restrict__ eidx,
    const int* __restrict__ esrc, const float* __restrict__ esc, const float* __restrict__ eattr,
    unsigned short* __restrict__ esc_hl, float4* __restrict__ y_s, int* __restrict__ src_s) {
  int wid = (blockIdx.x * 256 + threadIdx.x) >> 6;
  int lane = threadIdx.x & 63;
  if (wid >= N_NODES) return;
  int jb = row_start[wid], je = row_start[wid + 1];
  int deg = je - jb;
  if (deg <= 0) return;
  if (deg <= 64) {
    int key = (lane < deg) ? eidx[jb + lane] : 0x7fffffff;
#pragma unroll
    for (int k = 2; k <= 64; k <<= 1)
      for (int j = k >> 1; j > 0; j >>= 1) {
        int other = __shfl_xor(key, j, 64);
        bool asc = ((lane & k) == 0);
        bool upper = ((lane & j) != 0);
        key = (upper == asc) ? max(key, other) : min(key, other);
      }
    if (lane < deg) {
      int p = jb + lane, e = key;
      src_s[p] = esrc[e];
      y_s[p] = *(const float4*)(eattr + (size_t)e * 4);
      const float4* q = (const float4*)(esc + (size_t)e * 8);
      float4 a = q[0], b = q[1];
      float e8[8] = {a.x, a.y, a.z, a.w, b.x, b.y, b.z, b.w};
      s8v hi, lo;
#pragma unroll
      for (int j = 0; j < 8; ++j) {
        unsigned short h, l;
        split_rtz(e8[j], h, l);
        hi[j] = (short)h; lo[j] = (short)l;
      }
      *(s8v*)(esc_hl + (size_t)p * 16) = hi;
      *(s8v*)(esc_hl + (size_t)p * 16 + 8) = lo;
    }
  } else {
    if (lane == 0) {  // rare fallback
      for (int i = jb + 1; i < je; ++i) {
        int v = eidx[i];
        int j = i - 1;
        while (j >= jb && eidx[j] > v) { eidx[j + 1] = eidx[j]; --j; }
        eidx[j + 1] = v;
      }
    }
    for (int p = jb + lane; p < je; p += 64) {
      int e = eidx[p];
      src_s[p] = esrc[e];
      y_s[p] = *(const float4*)(eattr + (size_t)e * 4);
      const float4* q = (const float4*)(esc + (size_t)e * 8);
      float4 a = q[0], b = q[1];
      float e8[8] = {a.x, a.y, a.z, a.w, b.x, b.y, b.z, b.w};
      s8v hi, lo;
#pragma unroll
      for (int j = 0; j < 8; ++j) {
        unsigned short h, l;
        split_rtz(e8[j], h, l);
        hi[j] = (short)h; lo[j] = (short)l;
      }
      *(s8v*)(esc_hl + (size_t)p * 16) = hi;
      *(s8v*)(esc_hl + (size_t)p * 16 + 8) = lo;
    }
  }
}

// ---------------- node_pre: low-divergence compute, permuted store into interleaved layout -------
// s1v1 row: slot(0..15)*8 + {0:s1[slot],1:s1[slot+16],2+c:v1[slot][c],5+c:v1[slot+16][c]}
__global__ __launch_bounds__(256) void k_node_pre(const float* __restrict__ x,
    const float* __restrict__ l1s, const float* __restrict__ l1v,
    float* __restrict__ s1v1)
{
  int t = blockIdx.x * 256 + threadIdx.x;
  int node = t >> 7, j = t & 127;
  const float* xr = x + (size_t)node * 128;
  float acc = 0.f;
  int addr;
  if (j < 32) {
    int m = j;
#pragma unroll
    for (int u = 0; u < 32; ++u) acc += xr[u] * l1s[u * 32 + m];
    addr = (m & 15) * 8 + (m >> 4);
  } else {
    int jj = j - 32, m = jj / 3, c = jj - 3 * m;
#pragma unroll
    for (int u = 0; u < 32; ++u) acc += xr[32 + u * 3 + c] * l1v[u * 32 + m];
    addr = (m & 15) * 8 + 2 + (m >> 4) * 3 + c;
  }
  s1v1[(size_t)node * 128 + addr] = acc * 0.17677669529663689f;
}

// ---------------- fused edge MLP + per-node aggregation (1 wave = 1 dst node, no atomics) --------
// Verified-best configuration (r8/r13): stride-72 padded LDS, per-tile B LDS reads, (256,3),
// unconditional h writes (pad rows compute garbage that is never consumed — guards cause spills).
template<int MAT>
__global__ __launch_bounds__(256, 3) void k_edge_agg(
    const float* __restrict__ esc, const int* __restrict__ esrc, const float* __restrict__ eattr,
    const unsigned short* __restrict__ esc_hl, const int* __restrict__ src_s, const float4* __restrict__ y_s,
    const float* __restrict__ s1v1, const int* __restrict__ row_start, const int* __restrict__ eidx,
    const float* __restrict__ w1g, const float* __restrict__ w2g, const float* __restrict__ w3g,
    float* __restrict__ agg)
{
  __shared__ __attribute__((aligned(16))) unsigned short W2T[64 * 72];
  __shared__ __attribute__((aligned(16))) unsigned short W3T[128 * 72];
  __shared__ __attribute__((aligned(16))) unsigned short Hb[4][2][16 * 72];

  const int tid = threadIdx.x, lane = tid & 63, wv = tid >> 6;
  const int c0 = lane & 15, g = lane >> 4;

  for (int idx = tid; idx < 64 * 64; idx += 256) {
    int k = idx >> 6, n2 = idx & 63;
    W2T[n2 * 72 + k] = f2bf(w2g[idx] * 0.125f);      // exact pow2 fold
  }
  for (int idx = tid; idx < 64 * 128; idx += 256) {
    int k = idx >> 7, n2 = idx & 127;
    W3T[n2 * 72 + k] = f2bf(w3g[idx] * 0.125f);      // exact pow2 fold
  }
  // B1 carries 1/sqrt(8): hi/lo split of the scaled weight
  s8v B1[4];
#pragma unroll
  for (int nt = 0; nt < 4; ++nt)
#pragma unroll
    for (int i = 0; i < 8; ++i) {
      float w = w1g[i * 64 + nt * 16 + c0] * 0.35355339059327373f;
      unsigned short hi = f2bf(w);
      B1[nt][i] = (g < 2) ? (short)hi : (short)f2bf(w - bfh2f(hi));
    }
  __syncthreads();   // only block-wide barrier (weight staging)

  unsigned short* hhi = &Hb[wv][0][0];
  unsigned short* hlo = &Hb[wv][1][0];
  const f4v z = {0.f, 0.f, 0.f, 0.f};

  const int node = blockIdx.x * 4 + wv;
  const int jb = row_start[node], je = row_start[node + 1];

  float nacc[16];
#pragma unroll
  for (int k = 0; k < 16; ++k) nacc[k] = 0.f;

  for (int base = jb; base < je; base += 16) {
    const int nvalid = je - base;
    // ---- prefetch per-edge data
    s8v A1 = {0, 0, 0, 0, 0, 0, 0, 0};
    int srcv[4];
    float4 yv[4];
    bool val[4];
    if constexpr (MAT) {
      if (c0 < nvalid)
        A1 = *(const s8v*)(esc_hl + (size_t)(base + c0) * 16 + (size_t)(g & 1) * 8);
#pragma unroll
      for (int i = 0; i < 4; ++i) {
        int s = g * 4 + i;
        val[i] = (s < nvalid);
        srcv[i] = 0; yv[i] = make_float4(0.f, 0.f, 0.f, 0.f);
        if (val[i]) { srcv[i] = src_s[base + s]; yv[i] = y_s[base + s]; }
      }
    } else {
      if (c0 < nvalid) {
        int eid = eidx[base + c0];
        const float4* p = (const float4*)(esc + (size_t)eid * 8);
        float4 a = p[0], b = p[1];
        float e8[8] = {a.x, a.y, a.z, a.w, b.x, b.y, b.z, b.w};
#pragma unroll
        for (int j = 0; j < 8; ++j) {
          unsigned short h, l;
          split_rtz(e8[j], h, l);
          A1[j] = (g & 1) ? (short)l : (short)h;
        }
      }
#pragma unroll
      for (int i = 0; i < 4; ++i) {
        int s = g * 4 + i;
        val[i] = (s < nvalid);
        srcv[i] = 0; yv[i] = make_float4(0.f, 0.f, 0.f, 0.f);
        if (val[i]) {
          int eid = eidx[base + s];
          srcv[i] = esrc[eid];
          yv[i] = *(const float4*)(eattr + (size_t)eid * 4);
        }
      }
    }
    // ---- stage 1: h1 = ssp(es @ W1s)
#pragma unroll
    for (int nt = 0; nt < 4; ++nt) {
      f4v acc = __builtin_amdgcn_mfma_f32_16x16x32_bf16(A1, B1[nt], z, 0, 0, 0);
#pragma unroll
      for (int i = 0; i < 4; ++i) {
        float hv = sspf(acc[i]);
        unsigned short h, l;
        split_rtz(hv, h, l);
        hhi[(g * 4 + i) * 72 + nt * 16 + c0] = h;
        hlo[(g * 4 + i) * 72 + nt * 16 + c0] = l;
      }
    }
    // ---- stage 2: h2 = ssp(h1 @ W2s) (per-wave in-order DS; frags loaded before overwrite)
    s8v A2ah = *(const s8v*)&hhi[c0 * 72 + 8 * g];
    s8v A2bh = *(const s8v*)&hhi[c0 * 72 + 32 + 8 * g];
    s8v A2al = *(const s8v*)&hlo[c0 * 72 + 8 * g];
    s8v A2bl = *(const s8v*)&hlo[c0 * 72 + 32 + 8 * g];
#pragma unroll
    for (int nt = 0; nt < 4; ++nt) {
      s8v Ba = *(const s8v*)&W2T[(nt * 16 + c0) * 72 + 8 * g];
      s8v Bb = *(const s8v*)&W2T[(nt * 16 + c0) * 72 + 32 + 8 * g];
      f4v acc = __builtin_amdgcn_mfma_f32_16x16x32_bf16(A2ah, Ba, z, 0, 0, 0);
      acc = __builtin_amdgcn_mfma_f32_16x16x32_bf16(A2bh, Bb, acc, 0, 0, 0);
      acc = __builtin_amdgcn_mfma_f32_16x16x32_bf16(A2al, Ba, acc, 0, 0, 0);
      acc = __builtin_amdgcn_mfma_f32_16x16x32_bf16(A2bl, Bb, acc, 0, 0, 0);
#pragma unroll
      for (int i = 0; i < 4; ++i) {
        float hv = sspf(acc[i]);
        unsigned short h, l;
        split_rtz(hv, h, l);
        hhi[(g * 4 + i) * 72 + nt * 16 + c0] = h;
        hlo[(g * 4 + i) * 72 + nt * 16 + c0] = l;
      }
    }
    // ---- s1v1 row loads before stage 3 (latency hides under MFMAs)
    float4 pr0[4], pr1[4];
#pragma unroll
    for (int i = 0; i < 4; ++i) {
      if (val[i]) {
        const float* svp = s1v1 + (size_t)srcv[i] * 128 + c0 * 8;
        pr0[i] = *(const float4*)svp;
        pr1[i] = *(const float4*)(svp + 4);
      } else {
        pr0[i] = make_float4(0.f, 0.f, 0.f, 0.f);
        pr1[i] = make_float4(0.f, 0.f, 0.f, 0.f);
      }
    }
    // ---- stage 3: w = h2 @ W3s
    s8v A3ah = *(const s8v*)&hhi[c0 * 72 + 8 * g];
    s8v A3bh = *(const s8v*)&hhi[c0 * 72 + 32 + 8 * g];
    s8v A3al = *(const s8v*)&hlo[c0 * 72 + 8 * g];
    s8v A3bl = *(const s8v*)&hlo[c0 * 72 + 32 + 8 * g];
    f4v acc3[8];
#pragma unroll
    for (int nt = 0; nt < 8; ++nt) {
      s8v Ba = *(const s8v*)&W3T[(nt * 16 + c0) * 72 + 8 * g];
      s8v Bb = *(const s8v*)&W3T[(nt * 16 + c0) * 72 + 32 + 8 * g];
      acc3[nt] = __builtin_amdgcn_mfma_f32_16x16x32_bf16(A3ah, Ba, z, 0, 0, 0);
      acc3[nt] = __builtin_amdgcn_mfma_f32_16x16x32_bf16(A3bh, Bb, acc3[nt], 0, 0, 0);
      acc3[nt] = __builtin_amdgcn_mfma_f32_16x16x32_bf16(A3al, Ba, acc3[nt], 0, 0, 0);
      acc3[nt] = __builtin_amdgcn_mfma_f32_16x16x32_bf16(A3bl, Bb, acc3[nt], 0, 0, 0);
    }
    // ---- epilogue: accumulate per-lane partials (reduce deferred to end of node)
#pragma unroll
    for (int i = 0; i < 4; ++i) {
      if (val[i]) {
        float w0 = acc3[0][i], w1_ = acc3[1][i], w2_ = acc3[2][i], w3_ = acc3[3][i];
        float w4_ = acc3[4][i], w5_ = acc3[5][i], w6_ = acc3[6][i], w7_ = acc3[7][i];
        float4 y = yv[i];
        float sA = pr0[i].x, sB = pr0[i].y;
        float vA0 = pr0[i].z, vA1 = pr0[i].w, vA2 = pr1[i].x;
        float vB0 = pr1[i].y, vB1 = pr1[i].z, vB2 = pr1[i].w;
        nacc[0] += w0 * sA * y.x;
        nacc[1] += w1_ * sB * y.x;
        nacc[2] += w6_ * (vA0 * y.y + vA1 * y.z + vA2 * y.w);
        nacc[3] += w7_ * (vB0 * y.y + vB1 * y.z + vB2 * y.w);
        nacc[4] += w2_ * sA * y.y;  nacc[5] += w2_ * sA * y.z;  nacc[6] += w2_ * sA * y.w;
        nacc[7] += w3_ * sB * y.y;  nacc[8] += w3_ * sB * y.z;  nacc[9] += w3_ * sB * y.w;
        nacc[10] += w4_ * vA0 * y.x; nacc[11] += w4_ * vA1 * y.x; nacc[12] += w4_ * vA2 * y.x;
        nacc[13] += w5_ * vB0 * y.x; nacc[14] += w5_ * vB1 * y.x; nacc[15] += w5_ * vB2 * y.x;
      }
    }
  }
  // ---- one cross-lane reduce per node
#pragma unroll
  for (int k = 0; k < 16; ++k) {
    float v = nacc[k];
    v += __shfl_xor(v, 16, 64);
    v += __shfl_xor(v, 32, 64);
    nacc[k] = v;
  }
  if (g == 0) {
    float* ad = agg + (size_t)node * 256;
    ad[c0] = nacc[0];
    ad[16 + c0] = nacc[1];
    ad[32 + c0] = nacc[2];
    ad[48 + c0] = nacc[3];
#pragma unroll
    for (int c = 0; c < 3; ++c) {
      ad[64 + 3 * c0 + c]  = nacc[4 + c];
      ad[112 + 3 * c0 + c] = nacc[7 + c];
      ad[160 + 3 * c0 + c] = nacc[10 + c];
      ad[208 + 3 * c0 + c] = nacc[13 + c];
    }
  }
}

// ---------------- node_post: lin2 + self-connection + gate + residual ----------------
__global__ __launch_bounds__(256) void k_node_post(
    const float* __restrict__ x, const float* __restrict__ attr, const float* __restrict__ agg,
    const float* __restrict__ l2s, const float* __restrict__ l2v,
    const float* __restrict__ scs, const float* __restrict__ scv,
    float* __restrict__ out)
{
  __shared__ float xa[4][4][136];
  __shared__ float ag[4][4][256];
  const int l = threadIdx.x & 63, wv = threadIdx.x >> 6;
  const int n0 = blockIdx.x * 16 + wv * 4;
#pragma unroll
  for (int b = 0; b < 4; ++b) {
    int nd = n0 + b;
    xa[wv][b][l] = x[(size_t)nd * 128 + l];
    xa[wv][b][64 + l] = x[(size_t)nd * 128 + 64 + l];
    if (l < 8) xa[wv][b][128 + l] = attr[nd * 8 + l];
#pragma unroll
    for (int q = 0; q < 4; ++q) ag[wv][b][q * 64 + l] = agg[(size_t)nd * 256 + q * 64 + l];
  }
  float attr_r[4][8];
#pragma unroll
  for (int b = 0; b < 4; ++b)
#pragma unroll
    for (int a = 0; a < 8; ++a) attr_r[b][a] = xa[wv][b][128 + a];

  const int w1 = l / 3, c1 = l - 3 * w1;
  const int f2 = 64 + l;
  const int w2r = f2 / 3, c2r = f2 - 3 * w2r;
  const int w2 = (l < 32) ? w2r : 0, c2 = (l < 32) ? c2r : 0;

  float acc[4] = {0.f, 0.f, 0.f, 0.f}, sa[4] = {0.f, 0.f, 0.f, 0.f};
  float av1[4] = {0.f, 0.f, 0.f, 0.f}, sv1[4] = {0.f, 0.f, 0.f, 0.f};
  float av2[4] = {0.f, 0.f, 0.f, 0.f}, sv2[4] = {0.f, 0.f, 0.f, 0.f};

#pragma unroll 8
  for (int u = 0; u < 64; ++u) {
    float wl = l2s[u * 64 + l];
#pragma unroll
    for (int b = 0; b < 4; ++b) acc[b] += ag[wv][b][u] * wl;
  }
#pragma unroll 4
  for (int u = 0; u < 64; ++u) {
    float wla = l2v[u * 32 + w1];
    float wlb = l2v[u * 32 + w2];
#pragma unroll
    for (int b = 0; b < 4; ++b) {
      av1[b] += ag[wv][b][64 + 3 * u + c1] * wla;
      av2[b] += ag[wv][b][64 + 3 * u + c2] * wlb;
    }
  }
  for (int u = 0; u < 32; ++u) {
    float sb[4];
#pragma unroll
    for (int b = 0; b < 4; ++b) sb[b] = xa[wv][b][u];
#pragma unroll
    for (int a = 0; a < 8; ++a) {
      float wl = scs[(u * 8 + a) * 64 + l];
#pragma unroll
      for (int b = 0; b < 4; ++b) sa[b] += sb[b] * attr_r[b][a] * wl;
    }
  }
  for (int u = 0; u < 32; ++u) {
    float vb1[4], vb2[4];
#pragma unroll
    for (int b = 0; b < 4; ++b) {
      vb1[b] = xa[wv][b][32 + 3 * u + c1];
      vb2[b] = xa[wv][b][32 + 3 * u + c2];
    }
#pragma unroll
    for (int a = 0; a < 8; ++a) {
      float wla = scv[(u * 8 + a) * 32 + w1];
      float wlb = scv[(u * 8 + a) * 32 + w2];
#pragma unroll
      for (int b = 0; b < 4; ++b) {
        sv1[b] += vb1[b] * attr_r[b][a] * wla;
        sv2[b] += vb2[b] * attr_r[b][a] * wlb;
      }
    }
  }

#pragma unroll
  for (int b = 0; b < 4; ++b) {
    float outs = acc[b] * 0.03125f + sa[b] * 0.0625f;
    float gss = sspf(outs);
    float ov1 = av1[b] * 0.03125f + sv1[b] * 0.0625f;
    float ov2 = av2[b] * 0.03125f + sv2[b] * 0.0625f;
    float gate1 = __shfl(gss, 32 + w1, 64);
    float gate2 = __shfl(gss, 32 + w2, 64);
    float* o = out + (size_t)(n0 + b) * 128;
    if (l < 32) o[l] = xa[wv][b][l] + gss;
    o[32 + l] = xa[wv][b][32 + l] + ov1 * gate1;
    if (l < 32) o[96 + l] = xa[wv][b][96 + l] + ov2 * gate2;
  }
}

extern "C" void kernel_launch(void* const* d_in, const int* in_sizes, int n_in,
                              void* d_out, int out_size, void* d_ws, size_t ws_size,
                              hipStream_t stream) {
  const float* node_input = (const float*)d_in[0];
  const float* node_attr  = (const float*)d_in[1];
  const int*   esrc  = (const int*)d_in[2];
  const int*   edst  = (const int*)d_in[3];
  const float* eattr = (const float*)d_in[4];
  const float* escal = (const float*)d_in[5];
  const float* l1s = (const float*)d_in[6];
  const float* l1v = (const float*)d_in[7];
  const float* w1  = (const float*)d_in[8];
  const float* w2  = (const float*)d_in[9];
  const float* w3  = (const float*)d_in[10];
  const float* l2s = (const float*)d_in[11];
  const float* l2v = (const float*)d_in[12];
  const float* scs = (const float*)d_in[13];
  const float* scv = (const float*)d_in[14];
  float* out  = (float*)d_out;

  char* p = (char*)d_ws;
  float* s1v1 = (float*)p;                 p += (size_t)N_NODES * 128 * 4;
  float* agg  = (float*)p;                 p += (size_t)N_NODES * 256 * 4;
  int* eidx   = (int*)p;                   p += (size_t)N_EDGES * 4;
  unsigned short* esc_hl = (unsigned short*)p;  p += (size_t)N_EDGES * 16 * 2;
  float4* y_s = (float4*)p;                p += (size_t)N_EDGES * 16;
  int* src_s  = (int*)p;                   p += (size_t)N_EDGES * 4;
  size_t need_mat = (size_t)(p - (char*)d_ws) + (size_t)(N_NODES * 2 + 1) * 4;
  char* tail = ((size_t)ws_size >= need_mat) ? p : (char*)(eidx + N_EDGES);
  int* counts    = (int*)tail;
  int* row_start = counts + N_NODES;
  int* cursor    = row_start + N_NODES + 1;
  const bool use_mat = ((size_t)ws_size >= need_mat);

  (void)hipMemsetAsync(counts, 0, (size_t)N_NODES * sizeof(int), stream);
  k_hist<<<(N_EDGES + 255) / 256, 256, 0, stream>>>(edst, counts);
  k_scan<<<1, SCAN_T, 0, stream>>>(counts, row_start, cursor);
  k_scatter<<<(N_EDGES + 255) / 256, 256, 0, stream>>>(edst, cursor, eidx);
  if (use_mat)
    k_sortmat<<<(N_NODES * 64 + 255) / 256, 256, 0, stream>>>(row_start, eidx,
        esrc, escal, eattr, esc_hl, y_s, src_s);
  else
    k_sortseg<<<(N_NODES * 64 + 255) / 256, 256, 0, stream>>>(row_start, eidx);

  for (int layer = 0; layer < 3; ++layer) {
    const float* xin = (layer == 0) ? node_input : (const float*)out;
    k_node_pre<<<N_NODES * 128 / 256, 256, 0, stream>>>(
        xin, l1s + layer * 1024, l1v + layer * 1024, s1v1);
    if (use_mat)
      k_edge_agg<1><<<N_NODES / 4, 256, 0, stream>>>(escal, esrc, eattr, esc_hl, src_s, y_s,
          s1v1, row_start, eidx, w1 + layer * 512, w2 + layer * 4096, w3 + layer * 8192, agg);
    else
      k_edge_agg<0><<<N_NODES / 4, 256, 0, stream>>>(escal, esrc, eattr, esc_hl, src_s, y_s,
          s1v1, row_start, eidx, w1 + layer * 512, w2 + layer * 4096, w3 + layer * 8192, agg);
    k_node_post<<<N_NODES / 16, 256, 0, stream>>>(xin, node_attr, agg,
        l2s + layer * 4096, l2v + layer * 2048, scs + layer * 16384, scv + layer * 8192, out);
  }
}